// Round 6
// baseline (404.491 us; speedup 1.0000x reference)
//
#include <hip/hip_runtime.h>
#include <cmath>

#define BB 4
#define LL 2048
#define DD 1024
#define HH 8
#define MM (BB * LL)   // 8192 rows

struct Gammas { float lg2[8]; };
struct MMArgs { const ushort* Bt[4]; void* C[4]; void* C2[4]; int emode[4]; };

typedef __attribute__((ext_vector_type(8))) short bf16x8;
typedef __attribute__((ext_vector_type(4))) float f32x4;

__device__ __forceinline__ ushort f2bf(float f) {
    uint u = __builtin_bit_cast(uint, f);
    uint r = (u + 0x7fffu + ((u >> 16) & 1u)) >> 16;
    return (ushort)r;
}
__device__ __forceinline__ float bf2f(ushort h) {
    uint u = ((uint)h) << 16;
    return __builtin_bit_cast(float, u);
}
__device__ __forceinline__ void gload16(const void* g, void* l) {
    __builtin_amdgcn_global_load_lds((const __attribute__((address_space(1))) void*)g,
                                     (__attribute__((address_space(3))) void*)l, 16, 0, 0);
}

// ---------------------------------------------------------------------------
// xpos table: tbl[l*64 + i] = {cos*scale, sin*scale, cos/scale, sin/scale}
// ---------------------------------------------------------------------------
__global__ void xpos_table_kernel(float4* __restrict__ tbl) {
    int tid = blockIdx.x * blockDim.x + threadIdx.x;
    if (tid >= LL * 64) return;
    int l = tid >> 6, i = tid & 63;
    float inv = powf(10000.0f, -(float)i / 64.0f);
    float ang = (float)l * inv;
    float s = sinf(ang), c = cosf(ang);
    float base = (2.0f * (float)i + 51.2f) / 179.2f;
    float sc = powf(base, (float)l / 512.0f);
    tbl[tid] = make_float4(c * sc, s * sc, c / sc, s / sc);
}

__global__ __launch_bounds__(256) void cast_kernel(const float* __restrict__ X,
                                                   ushort* __restrict__ Xb) {
    int i = (blockIdx.x * 256 + threadIdx.x) * 4;
    float4 v = *(const float4*)&X[i];
    ushort4 o;
    o.x = f2bf(v.x); o.y = f2bf(v.y); o.z = f2bf(v.z); o.w = f2bf(v.w);
    *(ushort4*)&Xb[i] = o;
}

// ---------------------------------------------------------------------------
// Weight transpose+cast: W[k][n] (flat or per-head (h,d,e)) -> Wt[n][k] bf16
// ---------------------------------------------------------------------------
__global__ __launch_bounds__(256) void wtrans_kernel(const float* __restrict__ W,
                                                     ushort* __restrict__ Wt, int perhead) {
    __shared__ float T[64][68];
    const int k0 = blockIdx.y * 64, n0 = blockIdx.x * 64;
    const int t = threadIdx.x;
    for (int f = t; f < 64 * 16; f += 256) {
        int kk = f >> 4, s = f & 15;
        int n = n0 + s * 4;
        size_t src = perhead ? (size_t)(n >> 7) * 131072 + (size_t)(k0 + kk) * 128 + (n & 127)
                             : (size_t)(k0 + kk) * 1024 + n;
        *(float4*)&T[kk][s * 4] = *(const float4*)&W[src];
    }
    __syncthreads();
    for (int f = t; f < 64 * 8; f += 256) {
        int n = f >> 3, s = f & 7;
        __align__(16) ushort tmp[8];
        #pragma unroll
        for (int j = 0; j < 8; j++) tmp[j] = f2bf(T[s * 8 + j][n]);
        *(uint4*)&Wt[(size_t)(n0 + n) * 1024 + k0 + s * 8] = *(uint4*)tmp;
    }
}

// ---------------------------------------------------------------------------
// 256x256 bf16 MFMA GEMM, counted-vmcnt phase-split schedule (T3+T4+T2+T5).
// BK=32 per tile, 4 LDS buffers (depth-2 prefetch). Per K-step: 2 phases,
// each {issue prefetch loads for tile t+2 -> [phase A: vmcnt(6)] -> s_barrier
// -> ds_read (XOR-swizzled) -> setprio(1) -> 16 MFMA -> setprio(0)}.
// LDS dest is linear (global_load_lds requirement); the XOR swizzle
// (colunit ^= (row>>1)&3) is applied on the GLOBAL source address and on the
// ds_read address (rule: both-sides-or-neither).
// vmcnt ledger (per wave, 4 loads/tile, prologue stages tiles 0,1):
//   phase A of step t issues 2 -> outstanding <= tiles t(4),t+1(4),t+2(2)=10;
//   vmcnt(6) completes the oldest 4 = tile t.  Tail: vmcnt(4) then vmcnt(0).
// WAR: stage target (t+2)&3 was last read in step t-2, two barrier-pairs ago.
// ---------------------------------------------------------------------------
#define MM8_STEP(T, STAGE, VM)                                                  \
  {                                                                             \
    const int buf_ = (T) & 3;                                                   \
    const int sbuf_ = ((T) + 2) & 3;                                            \
    if (STAGE) {                                                                \
      const int nk_ = ((T) + 2) * 32;                                           \
      gload16(gA0 + nk_, &As[sbuf_][ldst]);                                     \
      gload16(gA1 + nk_, &As[sbuf_][4096 + ldst]);                              \
    }                                                                           \
    asm volatile("s_waitcnt vmcnt(" #VM ")" ::: "memory");                      \
    __builtin_amdgcn_sched_barrier(0);                                          \
    __builtin_amdgcn_s_barrier();                                               \
    __builtin_amdgcn_sched_barrier(0);                                          \
    bf16x8 am[8], bn[4];                                                        \
    _Pragma("unroll")                                                           \
    for (int mi = 0; mi < 4; mi++)                                              \
      am[mi] = *(const bf16x8*)&As[buf_][aoff + mi * 512];                      \
    _Pragma("unroll")                                                           \
    for (int ni = 0; ni < 4; ni++)                                              \
      bn[ni] = *(const bf16x8*)&Bs[buf_][boff + ni * 512];                      \
    __builtin_amdgcn_s_setprio(1);                                              \
    _Pragma("unroll")                                                           \
    for (int mi = 0; mi < 4; mi++)                                              \
      _Pragma("unroll")                                                         \
      for (int ni = 0; ni < 4; ni++)                                            \
        acc[mi][ni] = __builtin_amdgcn_mfma_f32_16x16x32_bf16(                  \
            am[mi], bn[ni], acc[mi][ni], 0, 0, 0);                              \
    __builtin_amdgcn_s_setprio(0);                                              \
    __builtin_amdgcn_sched_barrier(0);                                          \
    if (STAGE) {                                                                \
      const int nk_ = ((T) + 2) * 32;                                           \
      gload16(gB0 + nk_, &Bs[sbuf_][ldst]);                                     \
      gload16(gB1 + nk_, &Bs[sbuf_][4096 + ldst]);                              \
    }                                                                           \
    __builtin_amdgcn_sched_barrier(0);                                          \
    __builtin_amdgcn_s_barrier();                                               \
    __builtin_amdgcn_sched_barrier(0);                                          \
    _Pragma("unroll")                                                           \
    for (int mi = 4; mi < 8; mi++)                                              \
      am[mi] = *(const bf16x8*)&As[buf_][aoff + mi * 512];                      \
    __builtin_amdgcn_s_setprio(1);                                              \
    _Pragma("unroll")                                                           \
    for (int mi = 4; mi < 8; mi++)                                              \
      _Pragma("unroll")                                                         \
      for (int ni = 0; ni < 4; ni++)                                            \
        acc[mi][ni] = __builtin_amdgcn_mfma_f32_16x16x32_bf16(                  \
            am[mi], bn[ni], acc[mi][ni], 0, 0, 0);                              \
    __builtin_amdgcn_s_setprio(0);                                              \
  }

__global__ __launch_bounds__(512) void mm8_kernel(
    const ushort* __restrict__ A, MMArgs args, const float4* __restrict__ tbl)
{
    __shared__ __align__(16) ushort As[4][8192];   // 4 bufs x [256 rows][32]
    __shared__ __align__(16) ushort Bs[4][8192];
    const int t = threadIdx.x;
    const int w = t >> 6, lane = t & 63;
    const int ln = lane & 15, quad = lane >> 4;
    const int which = blockIdx.x >> 2;
    const ushort* Bt = args.Bt[which];
    void* Cv = args.C[which];
    void* Cv2 = args.C2[which];
    const int emode = args.emode[which];
    const int n0 = (blockIdx.x & 3) * 256, m0 = blockIdx.y * 256;
    const int wm = w & 1, wn = w >> 1;     // wave tile: 128 rows x 64 cols

    f32x4 acc[8][4];
    const f32x4 fzero = {0.f, 0.f, 0.f, 0.f};
    #pragma unroll
    for (int i = 0; i < 8; i++)
        #pragma unroll
        for (int j = 0; j < 4; j++) acc[i][j] = fzero;

    // staging: thread -> row = w*16 + (lane>>2) (+128 for 2nd half),
    // global col-unit pre-swizzled so LDS stays write-linear per wave.
    const int srow = w * 16 + (lane >> 2);
    const int scol = ((lane & 3) ^ ((lane >> 3) & 3)) * 8;
    const ushort* gA0 = A  + (size_t)(m0 + srow) * 1024 + scol;
    const ushort* gA1 = gA0 + (size_t)128 * 1024;
    const ushort* gB0 = Bt + (size_t)(n0 + srow) * 1024 + scol;
    const ushort* gB1 = gB0 + (size_t)128 * 1024;
    const int ldst = w * 512;              // wave-uniform LDS base (elements)

    // swizzled ds_read offsets: colunit = quad ^ ((row>>1)&3), row%16 == ln
    const int cQ = (quad ^ ((ln >> 1) & 3)) * 8;
    const int aoff = (wm * 128 + ln) * 32 + cQ;
    const int boff = (wn * 64 + ln) * 32 + cQ;

    // prologue: stage tiles 0 and 1 (issue order = tile order for vmcnt)
    #pragma unroll
    for (int tt = 0; tt < 2; ++tt) {
        gload16(gA0 + tt * 32, &As[tt][ldst]);
        gload16(gA1 + tt * 32, &As[tt][4096 + ldst]);
        gload16(gB0 + tt * 32, &Bs[tt][ldst]);
        gload16(gB1 + tt * 32, &Bs[tt][4096 + ldst]);
    }

    for (int T = 0; T < 30; ++T) {
        MM8_STEP(T, 1, 6);
    }
    MM8_STEP(30, 0, 4);
    MM8_STEP(31, 0, 0);

    #pragma unroll
    for (int mi = 0; mi < 8; mi++) {
        #pragma unroll
        for (int ni = 0; ni < 4; ni++) {
            const int row0 = m0 + wm * 128 + mi * 16 + quad * 4;
            const int e = wn * 64 + ni * 16 + ln;       // col within tile
            const int col = n0 + e;                     // 0..1023
            if (emode == 5) {
                const int b = row0 >> 11, l0 = row0 & (LL - 1);
                ushort4 pk;
                pk.x = f2bf(acc[mi][ni][0]); pk.y = f2bf(acc[mi][ni][1]);
                pk.z = f2bf(acc[mi][ni][2]); pk.w = f2bf(acc[mi][ni][3]);
                *(ushort4*)&((ushort*)Cv)[((size_t)(b * 1024 + col)) * 2048 + l0] = pk;
                continue;
            }
            float vv[4];
            #pragma unroll
            for (int r = 0; r < 4; r++) {
                float v = acc[mi][ni][r];
                if (emode == 1 || emode == 2 || emode == 6) {
                    float4 tt = tbl[(size_t)((row0 + r) & (LL - 1)) * 64 + ((col & 127) >> 1)];
                    float cc = (emode == 1) ? tt.x : tt.z;
                    float ss = (emode == 1) ? tt.y : tt.w;
                    float partner = __shfl_xor(v, 1);
                    float rot = (col & 1) ? partner : -partner;
                    v = v * cc + rot * ss;
                } else if (emode == 3) {
                    v = v / (1.0f + expf(-v));
                }
                vv[r] = v;
                if (emode == 4)
                    ((float*)Cv)[(size_t)(row0 + r) * 1024 + col] = v;
                else
                    ((ushort*)Cv)[(size_t)(row0 + r) * 1024 + col] = f2bf(v);
            }
            if (emode == 6) {
                const int b = row0 >> 11, l0 = row0 & (LL - 1);
                ushort4 pk;
                pk.x = f2bf(vv[0]); pk.y = f2bf(vv[1]);
                pk.z = f2bf(vv[2]); pk.w = f2bf(vv[3]);
                *(ushort4*)&((ushort*)Cv2)[((size_t)(b * 1024 + col)) * 2048 + l0] = pk;
            }
        }
    }
}

// ---------------------------------------------------------------------------
// bf16 MFMA GEMM (round-2 proven config): 128x128 tile, BK=32, 2-phase
// double-buffered LDS, one __syncthreads per K-step. Used for out-proj
// (512-block grid keeps all CUs busy at this N).
// ---------------------------------------------------------------------------
__global__ __launch_bounds__(256) void mm_kernel(
    const ushort* __restrict__ A, MMArgs args, const float4* __restrict__ tbl)
{
    __shared__ __align__(16) ushort As[2][128 * 32];
    __shared__ __align__(16) ushort Bs[2][128 * 32];
    const int t = threadIdx.x;
    const int w = t >> 6, lane = t & 63;
    const int ln = lane & 15, quad = lane >> 4;
    const int which = blockIdx.x >> 3;
    const ushort* Bt = args.Bt[which];
    void* Cv = args.C[which];
    const int emode = args.emode[which];
    const int n0 = (blockIdx.x & 7) * 128, m0 = blockIdx.y * 128;
    const int wm = w & 1, wn = w >> 1;

    f32x4 acc[4][4];
    const f32x4 fzero = {0.f, 0.f, 0.f, 0.f};
    #pragma unroll
    for (int i = 0; i < 4; i++)
        #pragma unroll
        for (int j = 0; j < 4; j++) acc[i][j] = fzero;

    const int srow = w * 32 + (lane >> 2);
    const int scol = (lane & 3) * 8;
    const ushort* ga  = A  + (size_t)(m0 + srow) * 1024 + scol;
    const ushort* ga2 = ga + 16 * 1024;
    const ushort* gb  = Bt + (size_t)(n0 + srow) * 1024 + scol;
    const ushort* gb2 = gb + 16 * 1024;
    const int lo1 = (w * 32) * 32;
    const int lo2 = (w * 32 + 16) * 32;

    gload16(ga, &As[0][lo1]);
    gload16(ga2, &As[0][lo2]);
    gload16(gb, &Bs[0][lo1]);
    gload16(gb2, &Bs[0][lo2]);
    __syncthreads();

    for (int kt = 0; kt < 1024; kt += 32) {
        const int cur = (kt >> 5) & 1;
        if (kt < 1024 - 32) {
            const int nk = kt + 32;
            gload16(ga + nk, &As[cur ^ 1][lo1]);
            gload16(ga2 + nk, &As[cur ^ 1][lo2]);
            gload16(gb + nk, &Bs[cur ^ 1][lo1]);
            gload16(gb2 + nk, &Bs[cur ^ 1][lo2]);
        }
        bf16x8 am[4], bn[4];
        #pragma unroll
        for (int i = 0; i < 4; i++)
            am[i] = *(const bf16x8*)&As[cur][(wm * 64 + i * 16 + ln) * 32 + quad * 8];
        #pragma unroll
        for (int i = 0; i < 4; i++)
            bn[i] = *(const bf16x8*)&Bs[cur][(wn * 64 + i * 16 + ln) * 32 + quad * 8];
        #pragma unroll
        for (int mi = 0; mi < 4; mi++)
            #pragma unroll
            for (int ni = 0; ni < 4; ni++)
                acc[mi][ni] = __builtin_amdgcn_mfma_f32_16x16x32_bf16(
                    am[mi], bn[ni], acc[mi][ni], 0, 0, 0);
        __syncthreads();
    }

    #pragma unroll
    for (int mi = 0; mi < 4; mi++) {
        #pragma unroll
        for (int ni = 0; ni < 4; ni++) {
            const int row0 = m0 + wm * 64 + mi * 16 + quad * 4;
            const int e = wn * 64 + ni * 16 + ln;
            const int col = n0 + e;
            #pragma unroll
            for (int r = 0; r < 4; r++) {
                float v = acc[mi][ni][r];
                if (emode == 3) v = v / (1.0f + expf(-v));
                if (emode == 4)
                    ((float*)Cv)[(size_t)(row0 + r) * 1024 + col] = v;
                else
                    ((ushort*)Cv)[(size_t)(row0 + r) * 1024 + col] = f2bf(v);
            }
        }
    }
}

// ---------------------------------------------------------------------------
// R1: per-chunk local state L_c^T[v][d] = sum_m gamma^{63-m} K~[m][d] V[m][v],
// one block per (bh, c). MFMA over m (k=64), LDS-bounced coalesced bf16 store.
// ---------------------------------------------------------------------------
__global__ __launch_bounds__(256) void state_kernel(
    const ushort* __restrict__ Ktb, const ushort* __restrict__ Vt,
    ushort* __restrict__ Sb, Gammas gp)
{
    __shared__ __align__(16) ushort shbuf[2 * 128 * 72];   // Ktl | Vwl, reused as Lsh
    ushort* Ktl = shbuf;
    ushort* Vwl = shbuf + 128 * 72;

    const int t = threadIdx.x;
    const int w = t >> 6, lane = t & 63, ln = lane & 15, quad = lane >> 4;
    const int c = blockIdx.x, bh = blockIdx.y;
    const int b = bh >> 3, h = bh & 7;
    const float lg2 = gp.lg2[h];
    const size_t tbase = ((size_t)b * 1024 + h * 128) * 2048 + (size_t)c * 64;

    const int sr = t >> 1, soff = (t & 1) * 32;
    #pragma unroll
    for (int j = 0; j < 4; j++)
        *(uint4*)&Ktl[sr * 72 + soff + j * 8] =
            *(const uint4*)&Ktb[tbase + (size_t)sr * 2048 + soff + j * 8];
    #pragma unroll
    for (int j = 0; j < 4; j++) {
        uint4 raw = *(const uint4*)&Vt[tbase + (size_t)sr * 2048 + soff + j * 8];
        ushort* rp = (ushort*)&raw;
        __align__(16) ushort tmp[8];
        #pragma unroll
        for (int jj = 0; jj < 8; jj++) {
            int m = soff + j * 8 + jj;
            tmp[jj] = f2bf(bf2f(rp[jj]) * exp2f(lg2 * (float)(63 - m)));
        }
        *(uint4*)&Vwl[sr * 72 + soff + j * 8] = *(uint4*)tmp;
    }
    __syncthreads();

    const int wm = w & 1, wn = w >> 1;
    f32x4 acc[4][4];
    const f32x4 fzero = {0.f, 0.f, 0.f, 0.f};
    #pragma unroll
    for (int i = 0; i < 4; i++)
        #pragma unroll
        for (int j = 0; j < 4; j++) acc[i][j] = fzero;

    #pragma unroll
    for (int ks = 0; ks < 2; ks++) {
        bf16x8 am[4], bn[4];
        #pragma unroll
        for (int mi = 0; mi < 4; mi++)
            am[mi] = *(const bf16x8*)&Ktl[(wm * 64 + mi * 16 + ln) * 72 + ks * 32 + quad * 8];
        #pragma unroll
        for (int ni = 0; ni < 4; ni++)
            bn[ni] = *(const bf16x8*)&Vwl[(wn * 64 + ni * 16 + ln) * 72 + ks * 32 + quad * 8];
        #pragma unroll
        for (int mi = 0; mi < 4; mi++)
            #pragma unroll
            for (int ni = 0; ni < 4; ni++)
                acc[mi][ni] = __builtin_amdgcn_mfma_f32_16x16x32_bf16(
                    am[mi], bn[ni], acc[mi][ni], 0, 0, 0);
    }
    __syncthreads();

    ushort* Lsh = shbuf;
    #pragma unroll
    for (int mi = 0; mi < 4; mi++) {
        #pragma unroll
        for (int ni = 0; ni < 4; ni++) {
            const int d0 = wm * 64 + mi * 16 + quad * 4;
            const int v = wn * 64 + ni * 16 + ln;
            ushort4 pk;
            pk.x = f2bf(acc[mi][ni][0]); pk.y = f2bf(acc[mi][ni][1]);
            pk.z = f2bf(acc[mi][ni][2]); pk.w = f2bf(acc[mi][ni][3]);
            *(ushort4*)&Lsh[v * 136 + d0] = pk;
        }
    }
    __syncthreads();
    ushort* dst = Sb + (size_t)(bh * 32 + c) * 128 * 128;
    const int orow = t >> 1, ooff = (t & 1) * 64;
    #pragma unroll
    for (int j = 0; j < 8; j++)
        *(uint4*)&dst[(size_t)orow * 128 + ooff + j * 8] =
            *(uint4*)&Lsh[orow * 136 + ooff + j * 8];
}

// ---------------------------------------------------------------------------
// R2: in-place scan over chunks: slot c-1 <- P_c = g64*P_{c-1} + L_{c-1}.
// ---------------------------------------------------------------------------
__global__ __launch_bounds__(256) void scan_kernel(ushort* __restrict__ Sb, Gammas gp)
{
    const int t = threadIdx.x;
    const int vb = blockIdx.x, bh = blockIdx.y;
    const int h = bh & 7;
    const float g64 = exp2f(64.0f * gp.lg2[h]);
    const int v = vb * 16 + (t >> 4);
    const int d0 = (t & 15) * 8;

    float acc[8];
    #pragma unroll
    for (int j = 0; j < 8; j++) acc[j] = 0.f;

    for (int c = 1; c < 32; c++) {
        ushort* p = Sb + ((size_t)(bh * 32 + (c - 1)) * 128 + v) * 128 + d0;
        uint4 lv = *(const uint4*)p;
        ushort* lp = (ushort*)&lv;
        __align__(16) ushort o[8];
        #pragma unroll
        for (int j = 0; j < 8; j++) {
            acc[j] = g64 * acc[j] + bf2f(lp[j]);
            o[j] = f2bf(acc[j]);
        }
        *(uint4*)p = *(uint4*)o;
    }
}

// ---------------------------------------------------------------------------
// R3: Y(chunk c) = gamma^{r+1} * Q~ . P_c  +  intra-chunk retention,
// fused GroupNorm + affine + silu-gate epilogue. One block per (bh, c).
// ---------------------------------------------------------------------------
__global__ __launch_bounds__(256) void ret2_kernel(
    const ushort* __restrict__ Qb, const ushort* __restrict__ Kb,
    const ushort* __restrict__ Vt, const ushort* __restrict__ Pt,
    const ushort* __restrict__ Gb,
    const float* __restrict__ gnw, const float* __restrict__ gnb,
    ushort* __restrict__ Z, Gammas gp)
{
    __shared__ __align__(16) ushort Ks[64 * 136];
    __shared__ __align__(16) ushort Vs[128 * 72];
    __shared__ __align__(16) ushort Ss[64 * 72];
    __shared__ __align__(16) ushort Ps[128 * 136];

    const int t = threadIdx.x;
    const int w = t >> 6, lane = t & 63, ln = lane & 15, quad = lane >> 4;
    const int c = blockIdx.x, bh = blockIdx.y;
    const int b = bh >> 3, h = bh & 7;
    const float lg2 = gp.lg2[h];
    const size_t qkbase = (size_t)b * LL * 1024 + (size_t)h * 128;
    const size_t vtbase = ((size_t)b * 1024 + h * 128) * 2048;
    const int n0 = c * 64;

    float dmk[4], drr[4];
    #pragma unroll
    for (int kt = 0; kt < 4; kt++)
        dmk[kt] = exp2f(-(float)(kt * 16 + quad * 4) * lg2);
    #pragma unroll
    for (int r = 0; r < 4; r++)
        drr[r] = exp2f(-(float)r * lg2);

    float gwv[8], gbv[8];
    #pragma unroll
    for (int vt = 0; vt < 8; vt++) {
        gwv[vt] = gnw[h * 128 + vt * 16 + ln];
        gbv[vt] = gnb[h * 128 + vt * 16 + ln];
    }

    const int krow = t >> 4, kc = (t & 15) * 8;
    const int vrow = t >> 3, vc = (t & 7) * 8;
    #pragma unroll
    for (int i = 0; i < 4; i++)
        *(uint4*)&Ks[(krow + i * 16) * 136 + kc] =
            *(const uint4*)&Kb[qkbase + (size_t)(n0 + krow + i * 16) * 1024 + kc];
    #pragma unroll
    for (int i = 0; i < 4; i++)
        *(uint4*)&Vs[(vrow + i * 32) * 72 + vc] =
            *(const uint4*)&Vt[vtbase + (size_t)(vrow + i * 32) * 2048 + n0 + vc];
    if (c > 0) {
        const ushort* psrc = Pt + (size_t)(bh * 32 + (c - 1)) * 128 * 128;
        const int pr = t >> 1, poff = (t & 1) * 64;
        #pragma unroll
        for (int j = 0; j < 8; j++)
            *(uint4*)&Ps[pr * 136 + poff + j * 8] =
                *(const uint4*)&psrc[(size_t)pr * 128 + poff + j * 8];
    }

    bf16x8 aq[4];
    #pragma unroll
    for (int ks = 0; ks < 4; ks++)
        aq[ks] = *(const bf16x8*)&Qb[qkbase + (size_t)(n0 + 16 * w + ln) * 1024
                                     + ks * 32 + quad * 8];
    f32x4 y[8];
    const f32x4 fzero = {0.f, 0.f, 0.f, 0.f};
    #pragma unroll
    for (int vt = 0; vt < 8; vt++) y[vt] = fzero;

    __syncthreads();

    if (c > 0) {
        #pragma unroll
        for (int ks = 0; ks < 4; ks++) {
            #pragma unroll
            for (int vt = 0; vt < 8; vt++) {
                bf16x8 bp = *(const bf16x8*)&Ps[(vt * 16 + ln) * 136 + ks * 32 + quad * 8];
                y[vt] = __builtin_amdgcn_mfma_f32_16x16x32_bf16(aq[ks], bp, y[vt], 0, 0, 0);
            }
        }
        #pragma unroll
        for (int rr = 0; rr < 4; rr++) {
            const float sc = exp2f(lg2 * (float)(16 * w + quad * 4 + rr + 1));
            #pragma unroll
            for (int vt = 0; vt < 8; vt++) y[vt][rr] *= sc;
        }
    }

    f32x4 s4[4];
    #pragma unroll
    for (int kt = 0; kt < 4; kt++) s4[kt] = fzero;
    #pragma unroll
    for (int ks = 0; ks < 4; ks++) {
        #pragma unroll
        for (int kt = 0; kt < 4; kt++) {
            bf16x8 bk = *(const bf16x8*)&Ks[(kt * 16 + ln) * 136 + ks * 32 + quad * 8];
            s4[kt] = __builtin_amdgcn_mfma_f32_16x16x32_bf16(bk, aq[ks], s4[kt], 0, 0, 0);
        }
    }
    const float dq = exp2f((float)(16 * w + ln) * lg2);
    #pragma unroll
    for (int kt = 0; kt < 4; kt++) {
        const float db = dq * dmk[kt];
        ushort4 pk;
        pk.x = f2bf((kt * 16 + quad * 4 + 0 <= 16 * w + ln) ? s4[kt][0] * db * drr[0] : 0.f);
        pk.y = f2bf((kt * 16 + quad * 4 + 1 <= 16 * w + ln) ? s4[kt][1] * db * drr[1] : 0.f);
        pk.z = f2bf((kt * 16 + quad * 4 + 2 <= 16 * w + ln) ? s4[kt][2] * db * drr[2] : 0.f);
        pk.w = f2bf((kt * 16 + quad * 4 + 3 <= 16 * w + ln) ? s4[kt][3] * db * drr[3] : 0.f);
        *(ushort4*)&Ss[(16 * w + ln) * 72 + kt * 16 + quad * 4] = pk;
    }
    #pragma unroll
    for (int ks2 = 0; ks2 < 2; ks2++) {
        bf16x8 as = *(const bf16x8*)&Ss[(16 * w + ln) * 72 + ks2 * 32 + quad * 8];
        #pragma unroll
        for (int vt = 0; vt < 8; vt++) {
            bf16x8 bv = *(const bf16x8*)&Vs[(vt * 16 + ln) * 72 + ks2 * 32 + quad * 8];
            y[vt] = __builtin_amdgcn_mfma_f32_16x16x32_bf16(as, bv, y[vt], 0, 0, 0);
        }
    }

    #pragma unroll
    for (int r = 0; r < 4; r++) {
        float s = 0.f, sq = 0.f;
        #pragma unroll
        for (int vt = 0; vt < 8; vt++) {
            float v = y[vt][r];
            s += v; sq += v * v;
        }
        #pragma unroll
        for (int off = 8; off >= 1; off >>= 1) {
            s  += __shfl_xor(s, off, 64);
            sq += __shfl_xor(sq, off, 64);
        }
        float mean = s * 0.0078125f;
        float var = sq * 0.0078125f - mean * mean;
        float rstd = rsqrtf(var + 1e-5f);
        const size_t row = (size_t)(b * LL + n0 + 16 * w + quad * 4 + r);
        #pragma unroll
        for (int vt = 0; vt < 8; vt++) {
            float gv = bf2f(Gb[row * 1024 + h * 128 + vt * 16 + ln]);
            float o = (y[vt][r] - mean) * rstd * gwv[vt] + gbv[vt];
            Z[row * 1024 + h * 128 + vt * 16 + ln] = f2bf(o * gv);
        }
    }
}

// ---------------------------------------------------------------------------
extern "C" void kernel_launch(void* const* d_in, const int* in_sizes, int n_in,
                              void* d_out, int out_size, void* d_ws, size_t ws_size,
                              hipStream_t stream) {
    const float* X   = (const float*)d_in[0];
    const float* Wq  = (const float*)d_in[1];
    const float* Wk  = (const float*)d_in[2];
    const float* Wv  = (const float*)d_in[3];
    const float* Wg  = (const float*)d_in[4];
    const float* Wo  = (const float*)d_in[5];
    const float* gnw = (const float*)d_in[6];
    const float* gnb = (const float*)d_in[7];
    float* out = (float*)d_out;

    const size_t MB = 1u << 20;
    char* base = (char*)d_ws;
    // Sb (32 MB, 0-32) overlays tbl/Xb/Wq..Wg, which die after the QKVG mm.
    ushort* Sb  = (ushort*)base;                        // 0-32  (L then P, bf16)
    float4* tbl = (float4*)base;                        // 0-2
    ushort* Xb  = (ushort*)(base + 2 * MB);             // 2-18
    ushort* Wqt = (ushort*)(base + 18 * MB);
    ushort* Wkt = (ushort*)(base + 20 * MB);
    ushort* Wvt = (ushort*)(base + 22 * MB);
    ushort* Wgt = (ushort*)(base + 24 * MB);
    ushort* Wot = (ushort*)(base + 32 * MB);            // 32-34
    ushort* Qb  = (ushort*)(base + 34 * MB);            // 34-50
    ushort* Kb  = (ushort*)(base + 50 * MB);            // 50-66
    ushort* Gb  = (ushort*)(base + 66 * MB);            // 66-82
    ushort* Vt  = (ushort*)(base + 82 * MB);            // 82-98
    ushort* Ktb = (ushort*)(base + 98 * MB);            // 98-114 (dead after R1)
    ushort* Zb  = (ushort*)(base + 98 * MB);            // reuses Ktb region in R3+

    Gammas gp;
    for (int h = 0; h < 8; h++) {
        double lin = log(1.0 / 32.0) +
                     (log(1.0 / 512.0) - log(1.0 / 32.0)) * (double)h / 7.0;
        float gamma = 1.0f - expf((float)lin);
        gp.lg2[h] = log2f(gamma);
    }

    xpos_table_kernel<<<(LL * 64) / 256, 256, 0, stream>>>(tbl);
    cast_kernel<<<MM * 1024 / 1024, 256, 0, stream>>>(X, Xb);

    dim3 wgrid(16, 16);
    wtrans_kernel<<<wgrid, 256, 0, stream>>>(Wq, Wqt, 1);
    wtrans_kernel<<<wgrid, 256, 0, stream>>>(Wk, Wkt, 1);
    wtrans_kernel<<<wgrid, 256, 0, stream>>>(Wv, Wvt, 1);
    wtrans_kernel<<<wgrid, 256, 0, stream>>>(Wg, Wgt, 0);
    wtrans_kernel<<<wgrid, 256, 0, stream>>>(Wo, Wot, 0);

    // fused Q/K/V/G projections (256^2 counted-vmcnt kernel):
    // x = which(4)*colblk(4), y = 8192/256 = 32 -> 512 blocks
    MMArgs qa;
    qa.Bt[0] = Wqt; qa.Bt[1] = Wkt; qa.Bt[2] = Wvt; qa.Bt[3] = Wgt;
    qa.C[0] = Qb;   qa.C[1] = Kb;   qa.C[2] = Vt;   qa.C[3] = Gb;
    qa.C2[0] = nullptr; qa.C2[1] = Ktb; qa.C2[2] = nullptr; qa.C2[3] = nullptr;
    qa.emode[0] = 1; qa.emode[1] = 6; qa.emode[2] = 5; qa.emode[3] = 3;
    mm8_kernel<<<dim3(16, 32), 512, 0, stream>>>(Xb, qa, tbl);

    // chunked-recurrent retention: local states -> scan -> per-chunk output
    state_kernel<<<dim3(32, 32), 256, 0, stream>>>(Ktb, Vt, Sb, gp);
    scan_kernel<<<dim3(8, 32), 256, 0, stream>>>(Sb, gp);
    ret2_kernel<<<dim3(32, 32), 256, 0, stream>>>(Qb, Kb, Vt, Sb, Gb,
                                                  gnw, gnb, Zb, gp);

    MMArgs oa;
    oa.Bt[0] = Wot; oa.Bt[1] = Wot; oa.Bt[2] = Wot; oa.Bt[3] = Wot;
    oa.C[0] = out;  oa.C[1] = out;  oa.C[2] = out;  oa.C[3] = out;
    oa.C2[0] = nullptr; oa.C2[1] = nullptr; oa.C2[2] = nullptr; oa.C2[3] = nullptr;
    oa.emode[0] = 4; oa.emode[1] = 4; oa.emode[2] = 4; oa.emode[3] = 4;
    mm_kernel<<<dim3(8, 64), 256, 0, stream>>>(Zb, oa, tbl);
}

// Round 7
// 404.244 us; speedup vs baseline: 1.0006x; 1.0006x over previous
//
#include <hip/hip_runtime.h>
#include <cmath>

#define BB 4
#define LL 2048
#define DD 1024
#define HH 8
#define MM (BB * LL)   // 8192 rows

struct Gammas { float lg2[8]; };
struct MMArgs { const ushort* Bt[4]; void* C[4]; void* C2[4]; int emode[4]; };

typedef __attribute__((ext_vector_type(8))) short bf16x8;
typedef __attribute__((ext_vector_type(4))) float f32x4;

__device__ __forceinline__ ushort f2bf(float f) {
    uint u = __builtin_bit_cast(uint, f);
    uint r = (u + 0x7fffu + ((u >> 16) & 1u)) >> 16;
    return (ushort)r;
}
__device__ __forceinline__ float bf2f(ushort h) {
    uint u = ((uint)h) << 16;
    return __builtin_bit_cast(float, u);
}
__device__ __forceinline__ void gload16(const void* g, void* l) {
    __builtin_amdgcn_global_load_lds((const __attribute__((address_space(1))) void*)g,
                                     (__attribute__((address_space(3))) void*)l, 16, 0, 0);
}

// ---------------------------------------------------------------------------
// xpos table: tbl[l*64 + i] = {cos*scale, sin*scale, cos/scale, sin/scale}
// ---------------------------------------------------------------------------
__global__ void xpos_table_kernel(float4* __restrict__ tbl) {
    int tid = blockIdx.x * blockDim.x + threadIdx.x;
    if (tid >= LL * 64) return;
    int l = tid >> 6, i = tid & 63;
    float inv = powf(10000.0f, -(float)i / 64.0f);
    float ang = (float)l * inv;
    float s = sinf(ang), c = cosf(ang);
    float base = (2.0f * (float)i + 51.2f) / 179.2f;
    float sc = powf(base, (float)l / 512.0f);
    tbl[tid] = make_float4(c * sc, s * sc, c / sc, s / sc);
}

__global__ __launch_bounds__(256) void cast_kernel(const float* __restrict__ X,
                                                   ushort* __restrict__ Xb) {
    int i = (blockIdx.x * 256 + threadIdx.x) * 4;
    float4 v = *(const float4*)&X[i];
    ushort4 o;
    o.x = f2bf(v.x); o.y = f2bf(v.y); o.z = f2bf(v.z); o.w = f2bf(v.w);
    *(ushort4*)&Xb[i] = o;
}

// ---------------------------------------------------------------------------
// Weight transpose+cast: W[k][n] (flat or per-head (h,d,e)) -> Wt[n][k] bf16
// ---------------------------------------------------------------------------
__global__ __launch_bounds__(256) void wtrans_kernel(const float* __restrict__ W,
                                                     ushort* __restrict__ Wt, int perhead) {
    __shared__ float T[64][68];
    const int k0 = blockIdx.y * 64, n0 = blockIdx.x * 64;
    const int t = threadIdx.x;
    for (int f = t; f < 64 * 16; f += 256) {
        int kk = f >> 4, s = f & 15;
        int n = n0 + s * 4;
        size_t src = perhead ? (size_t)(n >> 7) * 131072 + (size_t)(k0 + kk) * 128 + (n & 127)
                             : (size_t)(k0 + kk) * 1024 + n;
        *(float4*)&T[kk][s * 4] = *(const float4*)&W[src];
    }
    __syncthreads();
    for (int f = t; f < 64 * 8; f += 256) {
        int n = f >> 3, s = f & 7;
        __align__(16) ushort tmp[8];
        #pragma unroll
        for (int j = 0; j < 8; j++) tmp[j] = f2bf(T[s * 8 + j][n]);
        *(uint4*)&Wt[(size_t)(n0 + n) * 1024 + k0 + s * 8] = *(uint4*)tmp;
    }
}

// ---------------------------------------------------------------------------
// 256x256 bf16 MFMA GEMM, m201-style read-ahead schedule:
//  - per K-step (BK=32): phase-A MFMA (mi 0..3) uses regs loaded at the END
//    of the previous step (post-barrier read-ahead) -> LDS latency hidden
//    under the previous MFMA cluster + barrier wait;
//  - mid-step reads fetch amB (mi 4..7); post-barrier reads prefetch next
//    tile's amA + bn (bn double-buffered bn0/bn1, compile-time parity);
//  - counted s_waitcnt vmcnt(4) once/step (completes tile T+1 just before
//    its read-ahead), ONE s_barrier per step, 4 LDS buffers (stage target
//    (T+2)&3 never collides with readers of T or T+1);
//  - stage gloads split around the first MFMA cluster; setprio(1) on MFMA.
// Swizzle (round-6, verified conflict-free): global source col pre-swizzled,
// ds_read col swizzled, LDS dest linear (both-sides rule).
// vmcnt ledger (per wave, 4 loads/tile): prologue issues tiles 0,1 (8) ->
// vmcnt(4) completes t0. Step T issues 4 (tile T+2) -> outstanding
// {T+1:4, T+2:4}=8 -> vmcnt(4) completes T+1. T==30: vmcnt(0). T==31: none.
// ---------------------------------------------------------------------------
#define MM8_MFMA(AMV, BNV, OFS)                                                 \
    __builtin_amdgcn_s_setprio(1);                                              \
    _Pragma("unroll")                                                           \
    for (int mi = 0; mi < 4; mi++)                                              \
      _Pragma("unroll")                                                         \
      for (int ni = 0; ni < 4; ni++)                                            \
        acc[mi + (OFS)][ni] = __builtin_amdgcn_mfma_f32_16x16x32_bf16(          \
            AMV[mi], BNV[ni], acc[mi + (OFS)][ni], 0, 0, 0);                    \
    __builtin_amdgcn_s_setprio(0);

#define MM8_STEP(T, BNC, BNN)                                                   \
  {                                                                             \
    const int buf_ = (T) & 3, nbuf_ = ((T) + 1) & 3, sbuf_ = ((T) + 2) & 3;     \
    if ((T) < 30) {                                                             \
      const int nk_ = ((T) + 2) * 32;                                           \
      gload16(gA0 + nk_, &As[sbuf_][ldst]);                                     \
      gload16(gA1 + nk_, &As[sbuf_][4096 + ldst]);                              \
    }                                                                           \
    _Pragma("unroll")                                                           \
    for (int mi = 0; mi < 4; mi++)                                              \
      amB[mi] = *(const bf16x8*)&As[buf_][aoff + (mi + 4) * 512];               \
    MM8_MFMA(amA, BNC, 0)                                                       \
    if ((T) < 30) {                                                             \
      const int nk_ = ((T) + 2) * 32;                                           \
      gload16(gB0 + nk_, &Bs[sbuf_][ldst]);                                     \
      gload16(gB1 + nk_, &Bs[sbuf_][4096 + ldst]);                              \
    }                                                                           \
    if ((T) < 30)      asm volatile("s_waitcnt vmcnt(4)" ::: "memory");         \
    else if ((T) == 30) asm volatile("s_waitcnt vmcnt(0)" ::: "memory");        \
    __builtin_amdgcn_s_barrier();                                               \
    __builtin_amdgcn_sched_barrier(0);                                          \
    if ((T) < 31) {                                                             \
      _Pragma("unroll")                                                         \
      for (int mi = 0; mi < 4; mi++)                                            \
        amA[mi] = *(const bf16x8*)&As[nbuf_][aoff + mi * 512];                  \
      _Pragma("unroll")                                                         \
      for (int ni = 0; ni < 4; ni++)                                            \
        BNN[ni] = *(const bf16x8*)&Bs[nbuf_][boff + ni * 512];                  \
    }                                                                           \
    MM8_MFMA(amB, BNC, 4)                                                       \
  }

__global__ __launch_bounds__(512) void mm8_kernel(
    const ushort* __restrict__ A, MMArgs args, const float4* __restrict__ tbl)
{
    __shared__ __align__(16) ushort As[4][8192];   // 4 bufs x [256 rows][32]
    __shared__ __align__(16) ushort Bs[4][8192];
    const int t = threadIdx.x;
    const int w = t >> 6, lane = t & 63;
    const int ln = lane & 15, quad = lane >> 4;
    const int which = blockIdx.x >> 2;
    const ushort* Bt = args.Bt[which];
    void* Cv = args.C[which];
    void* Cv2 = args.C2[which];
    const int emode = args.emode[which];
    const int n0 = (blockIdx.x & 3) * 256, m0 = blockIdx.y * 256;
    const int wm = w & 1, wn = w >> 1;     // wave tile: 128 rows x 64 cols

    f32x4 acc[8][4];
    const f32x4 fzero = {0.f, 0.f, 0.f, 0.f};
    #pragma unroll
    for (int i = 0; i < 8; i++)
        #pragma unroll
        for (int j = 0; j < 4; j++) acc[i][j] = fzero;

    // staging: wave w covers rows {w*16.., +16} and {128+w*16..};
    // global col-unit pre-swizzled so LDS dest stays write-linear per wave.
    const int srow = w * 16 + (lane >> 2);
    const int scol = ((lane & 3) ^ ((lane >> 3) & 3)) * 8;
    const ushort* gA0 = A  + (size_t)(m0 + srow) * 1024 + scol;
    const ushort* gA1 = gA0 + (size_t)128 * 1024;
    const ushort* gB0 = Bt + (size_t)(n0 + srow) * 1024 + scol;
    const ushort* gB1 = gB0 + (size_t)128 * 1024;
    const int ldst = w * 512;              // wave-uniform LDS base (elements)

    // swizzled ds_read offsets: colunit = quad ^ ((row>>1)&3), row%16 == ln
    const int cQ = (quad ^ ((ln >> 1) & 3)) * 8;
    const int aoff = (wm * 128 + ln) * 32 + cQ;
    const int boff = (wn * 64 + ln) * 32 + cQ;

    bf16x8 amA[4], amB[4], bn0[4], bn1[4];

    // prologue: stage tiles 0 and 1 (issue order = tile order for vmcnt)
    #pragma unroll
    for (int tt = 0; tt < 2; ++tt) {
        gload16(gA0 + tt * 32, &As[tt][ldst]);
        gload16(gA1 + tt * 32, &As[tt][4096 + ldst]);
        gload16(gB0 + tt * 32, &Bs[tt][ldst]);
        gload16(gB1 + tt * 32, &Bs[tt][4096 + ldst]);
    }
    asm volatile("s_waitcnt vmcnt(4)" ::: "memory");   // tile 0 complete
    __builtin_amdgcn_s_barrier();
    __builtin_amdgcn_sched_barrier(0);
    #pragma unroll
    for (int mi = 0; mi < 4; mi++)
        amA[mi] = *(const bf16x8*)&As[0][aoff + mi * 512];
    #pragma unroll
    for (int ni = 0; ni < 4; ni++)
        bn0[ni] = *(const bf16x8*)&Bs[0][boff + ni * 512];

    for (int T2 = 0; T2 < 32; T2 += 2) {
        MM8_STEP(T2,     bn0, bn1)
        MM8_STEP(T2 + 1, bn1, bn0)
    }

    #pragma unroll
    for (int mi = 0; mi < 8; mi++) {
        #pragma unroll
        for (int ni = 0; ni < 4; ni++) {
            const int row0 = m0 + wm * 128 + mi * 16 + quad * 4;
            const int e = wn * 64 + ni * 16 + ln;       // col within tile
            const int col = n0 + e;                     // 0..1023
            if (emode == 5) {
                const int b = row0 >> 11, l0 = row0 & (LL - 1);
                ushort4 pk;
                pk.x = f2bf(acc[mi][ni][0]); pk.y = f2bf(acc[mi][ni][1]);
                pk.z = f2bf(acc[mi][ni][2]); pk.w = f2bf(acc[mi][ni][3]);
                *(ushort4*)&((ushort*)Cv)[((size_t)(b * 1024 + col)) * 2048 + l0] = pk;
                continue;
            }
            float vv[4];
            #pragma unroll
            for (int r = 0; r < 4; r++) {
                float v = acc[mi][ni][r];
                if (emode == 1 || emode == 2 || emode == 6) {
                    float4 tt = tbl[(size_t)((row0 + r) & (LL - 1)) * 64 + ((col & 127) >> 1)];
                    float cc = (emode == 1) ? tt.x : tt.z;
                    float ss = (emode == 1) ? tt.y : tt.w;
                    float partner = __shfl_xor(v, 1);
                    float rot = (col & 1) ? partner : -partner;
                    v = v * cc + rot * ss;
                } else if (emode == 3) {
                    v = v / (1.0f + expf(-v));
                }
                vv[r] = v;
                if (emode == 4)
                    ((float*)Cv)[(size_t)(row0 + r) * 1024 + col] = v;
                else
                    ((ushort*)Cv)[(size_t)(row0 + r) * 1024 + col] = f2bf(v);
            }
            if (emode == 6) {
                const int b = row0 >> 11, l0 = row0 & (LL - 1);
                ushort4 pk;
                pk.x = f2bf(vv[0]); pk.y = f2bf(vv[1]);
                pk.z = f2bf(vv[2]); pk.w = f2bf(vv[3]);
                *(ushort4*)&((ushort*)Cv2)[((size_t)(b * 1024 + col)) * 2048 + l0] = pk;
            }
        }
    }
}

// ---------------------------------------------------------------------------
// bf16 MFMA GEMM (proven config): 128x128 tile, BK=32, 2-phase double-
// buffered LDS, one __syncthreads per K-step. Used for out-proj.
// ---------------------------------------------------------------------------
__global__ __launch_bounds__(256) void mm_kernel(
    const ushort* __restrict__ A, MMArgs args, const float4* __restrict__ tbl)
{
    __shared__ __align__(16) ushort As[2][128 * 32];
    __shared__ __align__(16) ushort Bs[2][128 * 32];
    const int t = threadIdx.x;
    const int w = t >> 6, lane = t & 63;
    const int ln = lane & 15, quad = lane >> 4;
    const int which = blockIdx.x >> 3;
    const ushort* Bt = args.Bt[which];
    void* Cv = args.C[which];
    const int emode = args.emode[which];
    const int n0 = (blockIdx.x & 7) * 128, m0 = blockIdx.y * 128;
    const int wm = w & 1, wn = w >> 1;

    f32x4 acc[4][4];
    const f32x4 fzero = {0.f, 0.f, 0.f, 0.f};
    #pragma unroll
    for (int i = 0; i < 4; i++)
        #pragma unroll
        for (int j = 0; j < 4; j++) acc[i][j] = fzero;

    const int srow = w * 32 + (lane >> 2);
    const int scol = (lane & 3) * 8;
    const ushort* ga  = A  + (size_t)(m0 + srow) * 1024 + scol;
    const ushort* ga2 = ga + 16 * 1024;
    const ushort* gb  = Bt + (size_t)(n0 + srow) * 1024 + scol;
    const ushort* gb2 = gb + 16 * 1024;
    const int lo1 = (w * 32) * 32;
    const int lo2 = (w * 32 + 16) * 32;

    gload16(ga, &As[0][lo1]);
    gload16(ga2, &As[0][lo2]);
    gload16(gb, &Bs[0][lo1]);
    gload16(gb2, &Bs[0][lo2]);
    __syncthreads();

    for (int kt = 0; kt < 1024; kt += 32) {
        const int cur = (kt >> 5) & 1;
        if (kt < 1024 - 32) {
            const int nk = kt + 32;
            gload16(ga + nk, &As[cur ^ 1][lo1]);
            gload16(ga2 + nk, &As[cur ^ 1][lo2]);
            gload16(gb + nk, &Bs[cur ^ 1][lo1]);
            gload16(gb2 + nk, &Bs[cur ^ 1][lo2]);
        }
        bf16x8 am[4], bn[4];
        #pragma unroll
        for (int i = 0; i < 4; i++)
            am[i] = *(const bf16x8*)&As[cur][(wm * 64 + i * 16 + ln) * 32 + quad * 8];
        #pragma unroll
        for (int i = 0; i < 4; i++)
            bn[i] = *(const bf16x8*)&Bs[cur][(wn * 64 + i * 16 + ln) * 32 + quad * 8];
        #pragma unroll
        for (int mi = 0; mi < 4; mi++)
            #pragma unroll
            for (int ni = 0; ni < 4; ni++)
                acc[mi][ni] = __builtin_amdgcn_mfma_f32_16x16x32_bf16(
                    am[mi], bn[ni], acc[mi][ni], 0, 0, 0);
        __syncthreads();
    }

    #pragma unroll
    for (int mi = 0; mi < 4; mi++) {
        #pragma unroll
        for (int ni = 0; ni < 4; ni++) {
            const int row0 = m0 + wm * 64 + mi * 16 + quad * 4;
            const int e = wn * 64 + ni * 16 + ln;
            const int col = n0 + e;
            #pragma unroll
            for (int r = 0; r < 4; r++) {
                float v = acc[mi][ni][r];
                if (emode == 3) v = v / (1.0f + expf(-v));
                if (emode == 4)
                    ((float*)Cv)[(size_t)(row0 + r) * 1024 + col] = v;
                else
                    ((ushort*)Cv)[(size_t)(row0 + r) * 1024 + col] = f2bf(v);
            }
        }
    }
}

// ---------------------------------------------------------------------------
// R1: per-chunk local state L_c^T[v][d] = sum_m gamma^{63-m} K~[m][d] V[m][v],
// one block per (bh, c). MFMA over m (k=64), LDS-bounced coalesced bf16 store.
// ---------------------------------------------------------------------------
__global__ __launch_bounds__(256) void state_kernel(
    const ushort* __restrict__ Ktb, const ushort* __restrict__ Vt,
    ushort* __restrict__ Sb, Gammas gp)
{
    __shared__ __align__(16) ushort shbuf[2 * 128 * 72];   // Ktl | Vwl, reused as Lsh
    ushort* Ktl = shbuf;
    ushort* Vwl = shbuf + 128 * 72;

    const int t = threadIdx.x;
    const int w = t >> 6, lane = t & 63, ln = lane & 15, quad = lane >> 4;
    const int c = blockIdx.x, bh = blockIdx.y;
    const int b = bh >> 3, h = bh & 7;
    const float lg2 = gp.lg2[h];
    const size_t tbase = ((size_t)b * 1024 + h * 128) * 2048 + (size_t)c * 64;

    const int sr = t >> 1, soff = (t & 1) * 32;
    #pragma unroll
    for (int j = 0; j < 4; j++)
        *(uint4*)&Ktl[sr * 72 + soff + j * 8] =
            *(const uint4*)&Ktb[tbase + (size_t)sr * 2048 + soff + j * 8];
    #pragma unroll
    for (int j = 0; j < 4; j++) {
        uint4 raw = *(const uint4*)&Vt[tbase + (size_t)sr * 2048 + soff + j * 8];
        ushort* rp = (ushort*)&raw;
        __align__(16) ushort tmp[8];
        #pragma unroll
        for (int jj = 0; jj < 8; jj++) {
            int m = soff + j * 8 + jj;
            tmp[jj] = f2bf(bf2f(rp[jj]) * exp2f(lg2 * (float)(63 - m)));
        }
        *(uint4*)&Vwl[sr * 72 + soff + j * 8] = *(uint4*)tmp;
    }
    __syncthreads();

    const int wm = w & 1, wn = w >> 1;
    f32x4 acc[4][4];
    const f32x4 fzero = {0.f, 0.f, 0.f, 0.f};
    #pragma unroll
    for (int i = 0; i < 4; i++)
        #pragma unroll
        for (int j = 0; j < 4; j++) acc[i][j] = fzero;

    #pragma unroll
    for (int ks = 0; ks < 2; ks++) {
        bf16x8 am[4], bn[4];
        #pragma unroll
        for (int mi = 0; mi < 4; mi++)
            am[mi] = *(const bf16x8*)&Ktl[(wm * 64 + mi * 16 + ln) * 72 + ks * 32 + quad * 8];
        #pragma unroll
        for (int ni = 0; ni < 4; ni++)
            bn[ni] = *(const bf16x8*)&Vwl[(wn * 64 + ni * 16 + ln) * 72 + ks * 32 + quad * 8];
        #pragma unroll
        for (int mi = 0; mi < 4; mi++)
            #pragma unroll
            for (int ni = 0; ni < 4; ni++)
                acc[mi][ni] = __builtin_amdgcn_mfma_f32_16x16x32_bf16(
                    am[mi], bn[ni], acc[mi][ni], 0, 0, 0);
    }
    __syncthreads();

    ushort* Lsh = shbuf;
    #pragma unroll
    for (int mi = 0; mi < 4; mi++) {
        #pragma unroll
        for (int ni = 0; ni < 4; ni++) {
            const int d0 = wm * 64 + mi * 16 + quad * 4;
            const int v = wn * 64 + ni * 16 + ln;
            ushort4 pk;
            pk.x = f2bf(acc[mi][ni][0]); pk.y = f2bf(acc[mi][ni][1]);
            pk.z = f2bf(acc[mi][ni][2]); pk.w = f2bf(acc[mi][ni][3]);
            *(ushort4*)&Lsh[v * 136 + d0] = pk;
        }
    }
    __syncthreads();
    ushort* dst = Sb + (size_t)(bh * 32 + c) * 128 * 128;
    const int orow = t >> 1, ooff = (t & 1) * 64;
    #pragma unroll
    for (int j = 0; j < 8; j++)
        *(uint4*)&dst[(size_t)orow * 128 + ooff + j * 8] =
            *(uint4*)&Lsh[orow * 136 + ooff + j * 8];
}

// ---------------------------------------------------------------------------
// R2: in-place scan over chunks: slot c-1 <- P_c = g64*P_{c-1} + L_{c-1}.
// ---------------------------------------------------------------------------
__global__ __launch_bounds__(256) void scan_kernel(ushort* __restrict__ Sb, Gammas gp)
{
    const int t = threadIdx.x;
    const int vb = blockIdx.x, bh = blockIdx.y;
    const int h = bh & 7;
    const float g64 = exp2f(64.0f * gp.lg2[h]);
    const int v = vb * 16 + (t >> 4);
    const int d0 = (t & 15) * 8;

    float acc[8];
    #pragma unroll
    for (int j = 0; j < 8; j++) acc[j] = 0.f;

    for (int c = 1; c < 32; c++) {
        ushort* p = Sb + ((size_t)(bh * 32 + (c - 1)) * 128 + v) * 128 + d0;
        uint4 lv = *(const uint4*)p;
        ushort* lp = (ushort*)&lv;
        __align__(16) ushort o[8];
        #pragma unroll
        for (int j = 0; j < 8; j++) {
            acc[j] = g64 * acc[j] + bf2f(lp[j]);
            o[j] = f2bf(acc[j]);
        }
        *(uint4*)p = *(uint4*)o;
    }
}

// ---------------------------------------------------------------------------
// R3: Y(chunk c) = gamma^{r+1} * Q~ . P_c  +  intra-chunk retention,
// fused GroupNorm + affine + silu-gate epilogue. One block per (bh, c).
// ---------------------------------------------------------------------------
__global__ __launch_bounds__(256) void ret2_kernel(
    const ushort* __restrict__ Qb, const ushort* __restrict__ Kb,
    const ushort* __restrict__ Vt, const ushort* __restrict__ Pt,
    const ushort* __restrict__ Gb,
    const float* __restrict__ gnw, const float* __restrict__ gnb,
    ushort* __restrict__ Z, Gammas gp)
{
    __shared__ __align__(16) ushort Ks[64 * 136];
    __shared__ __align__(16) ushort Vs[128 * 72];
    __shared__ __align__(16) ushort Ss[64 * 72];
    __shared__ __align__(16) ushort Ps[128 * 136];

    const int t = threadIdx.x;
    const int w = t >> 6, lane = t & 63, ln = lane & 15, quad = lane >> 4;
    const int c = blockIdx.x, bh = blockIdx.y;
    const int b = bh >> 3, h = bh & 7;
    const float lg2 = gp.lg2[h];
    const size_t qkbase = (size_t)b * LL * 1024 + (size_t)h * 128;
    const size_t vtbase = ((size_t)b * 1024 + h * 128) * 2048;
    const int n0 = c * 64;

    float dmk[4], drr[4];
    #pragma unroll
    for (int kt = 0; kt < 4; kt++)
        dmk[kt] = exp2f(-(float)(kt * 16 + quad * 4) * lg2);
    #pragma unroll
    for (int r = 0; r < 4; r++)
        drr[r] = exp2f(-(float)r * lg2);

    float gwv[8], gbv[8];
    #pragma unroll
    for (int vt = 0; vt < 8; vt++) {
        gwv[vt] = gnw[h * 128 + vt * 16 + ln];
        gbv[vt] = gnb[h * 128 + vt * 16 + ln];
    }

    const int krow = t >> 4, kc = (t & 15) * 8;
    const int vrow = t >> 3, vc = (t & 7) * 8;
    #pragma unroll
    for (int i = 0; i < 4; i++)
        *(uint4*)&Ks[(krow + i * 16) * 136 + kc] =
            *(const uint4*)&Kb[qkbase + (size_t)(n0 + krow + i * 16) * 1024 + kc];
    #pragma unroll
    for (int i = 0; i < 4; i++)
        *(uint4*)&Vs[(vrow + i * 32) * 72 + vc] =
            *(const uint4*)&Vt[vtbase + (size_t)(vrow + i * 32) * 2048 + n0 + vc];
    if (c > 0) {
        const ushort* psrc = Pt + (size_t)(bh * 32 + (c - 1)) * 128 * 128;
        const int pr = t >> 1, poff = (t & 1) * 64;
        #pragma unroll
        for (int j = 0; j < 8; j++)
            *(uint4*)&Ps[pr * 136 + poff + j * 8] =
                *(const uint4*)&psrc[(size_t)pr * 128 + poff + j * 8];
    }

    bf16x8 aq[4];
    #pragma unroll
    for (int ks = 0; ks < 4; ks++)
        aq[ks] = *(const bf16x8*)&Qb[qkbase + (size_t)(n0 + 16 * w + ln) * 1024
                                     + ks * 32 + quad * 8];
    f32x4 y[8];
    const f32x4 fzero = {0.f, 0.f, 0.f, 0.f};
    #pragma unroll
    for (int vt = 0; vt < 8; vt++) y[vt] = fzero;

    __syncthreads();

    if (c > 0) {
        #pragma unroll
        for (int ks = 0; ks < 4; ks++) {
            #pragma unroll
            for (int vt = 0; vt < 8; vt++) {
                bf16x8 bp = *(const bf16x8*)&Ps[(vt * 16 + ln) * 136 + ks * 32 + quad * 8];
                y[vt] = __builtin_amdgcn_mfma_f32_16x16x32_bf16(aq[ks], bp, y[vt], 0, 0, 0);
            }
        }
        #pragma unroll
        for (int rr = 0; rr < 4; rr++) {
            const float sc = exp2f(lg2 * (float)(16 * w + quad * 4 + rr + 1));
            #pragma unroll
            for (int vt = 0; vt < 8; vt++) y[vt][rr] *= sc;
        }
    }

    f32x4 s4[4];
    #pragma unroll
    for (int kt = 0; kt < 4; kt++) s4[kt] = fzero;
    #pragma unroll
    for (int ks = 0; ks < 4; ks++) {
        #pragma unroll
        for (int kt = 0; kt < 4; kt++) {
            bf16x8 bk = *(const bf16x8*)&Ks[(kt * 16 + ln) * 136 + ks * 32 + quad * 8];
            s4[kt] = __builtin_amdgcn_mfma_f32_16x16x32_bf16(bk, aq[ks], s4[kt], 0, 0, 0);
        }
    }
    const float dq = exp2f((float)(16 * w + ln) * lg2);
    #pragma unroll
    for (int kt = 0; kt < 4; kt++) {
        const float db = dq * dmk[kt];
        ushort4 pk;
        pk.x = f2bf((kt * 16 + quad * 4 + 0 <= 16 * w + ln) ? s4[kt][0] * db * drr[0] : 0.f);
        pk.y = f2bf((kt * 16 + quad * 4 + 1 <= 16 * w + ln) ? s4[kt][1] * db * drr[1] : 0.f);
        pk.z = f2bf((kt * 16 + quad * 4 + 2 <= 16 * w + ln) ? s4[kt][2] * db * drr[2] : 0.f);
        pk.w = f2bf((kt * 16 + quad * 4 + 3 <= 16 * w + ln) ? s4[kt][3] * db * drr[3] : 0.f);
        *(ushort4*)&Ss[(16 * w + ln) * 72 + kt * 16 + quad * 4] = pk;
    }
    #pragma unroll
    for (int ks2 = 0; ks2 < 2; ks2++) {
        bf16x8 as = *(const bf16x8*)&Ss[(16 * w + ln) * 72 + ks2 * 32 + quad * 8];
        #pragma unroll
        for (int vt = 0; vt < 8; vt++) {
            bf16x8 bv = *(const bf16x8*)&Vs[(vt * 16 + ln) * 72 + ks2 * 32 + quad * 8];
            y[vt] = __builtin_amdgcn_mfma_f32_16x16x32_bf16(as, bv, y[vt], 0, 0, 0);
        }
    }

    #pragma unroll
    for (int r = 0; r < 4; r++) {
        float s = 0.f, sq = 0.f;
        #pragma unroll
        for (int vt = 0; vt < 8; vt++) {
            float v = y[vt][r];
            s += v; sq += v * v;
        }
        #pragma unroll
        for (int off = 8; off >= 1; off >>= 1) {
            s  += __shfl_xor(s, off, 64);
            sq += __shfl_xor(sq, off, 64);
        }
        float mean = s * 0.0078125f;
        float var = sq * 0.0078125f - mean * mean;
        float rstd = rsqrtf(var + 1e-5f);
        const size_t row = (size_t)(b * LL + n0 + 16 * w + quad * 4 + r);
        #pragma unroll
        for (int vt = 0; vt < 8; vt++) {
            float gv = bf2f(Gb[row * 1024 + h * 128 + vt * 16 + ln]);
            float o = (y[vt][r] - mean) * rstd * gwv[vt] + gbv[vt];
            Z[row * 1024 + h * 128 + vt * 16 + ln] = f2bf(o * gv);
        }
    }
}

// ---------------------------------------------------------------------------
extern "C" void kernel_launch(void* const* d_in, const int* in_sizes, int n_in,
                              void* d_out, int out_size, void* d_ws, size_t ws_size,
                              hipStream_t stream) {
    const float* X   = (const float*)d_in[0];
    const float* Wq  = (const float*)d_in[1];
    const float* Wk  = (const float*)d_in[2];
    const float* Wv  = (const float*)d_in[3];
    const float* Wg  = (const float*)d_in[4];
    const float* Wo  = (const float*)d_in[5];
    const float* gnw = (const float*)d_in[6];
    const float* gnb = (const float*)d_in[7];
    float* out = (float*)d_out;

    const size_t MB = 1u << 20;
    char* base = (char*)d_ws;
    // Sb (32 MB, 0-32) overlays tbl/Xb/Wq..Wg, which die after the QKVG mm.
    ushort* Sb  = (ushort*)base;                        // 0-32  (L then P, bf16)
    float4* tbl = (float4*)base;                        // 0-2
    ushort* Xb  = (ushort*)(base + 2 * MB);             // 2-18
    ushort* Wqt = (ushort*)(base + 18 * MB);
    ushort* Wkt = (ushort*)(base + 20 * MB);
    ushort* Wvt = (ushort*)(base + 22 * MB);
    ushort* Wgt = (ushort*)(base + 24 * MB);
    ushort* Wot = (ushort*)(base + 32 * MB);            // 32-34
    ushort* Qb  = (ushort*)(base + 34 * MB);            // 34-50
    ushort* Kb  = (ushort*)(base + 50 * MB);            // 50-66
    ushort* Gb  = (ushort*)(base + 66 * MB);            // 66-82
    ushort* Vt  = (ushort*)(base + 82 * MB);            // 82-98
    ushort* Ktb = (ushort*)(base + 98 * MB);            // 98-114 (dead after R1)
    ushort* Zb  = (ushort*)(base + 98 * MB);            // reuses Ktb region in R3+

    Gammas gp;
    for (int h = 0; h < 8; h++) {
        double lin = log(1.0 / 32.0) +
                     (log(1.0 / 512.0) - log(1.0 / 32.0)) * (double)h / 7.0;
        float gamma = 1.0f - expf((float)lin);
        gp.lg2[h] = log2f(gamma);
    }

    xpos_table_kernel<<<(LL * 64) / 256, 256, 0, stream>>>(tbl);
    cast_kernel<<<MM * 1024 / 1024, 256, 0, stream>>>(X, Xb);

    dim3 wgrid(16, 16);
    wtrans_kernel<<<wgrid, 256, 0, stream>>>(Wq, Wqt, 1);
    wtrans_kernel<<<wgrid, 256, 0, stream>>>(Wk, Wkt, 1);
    wtrans_kernel<<<wgrid, 256, 0, stream>>>(Wv, Wvt, 1);
    wtrans_kernel<<<wgrid, 256, 0, stream>>>(Wg, Wgt, 0);
    wtrans_kernel<<<wgrid, 256, 0, stream>>>(Wo, Wot, 0);

    // fused Q/K/V/G projections (256^2 read-ahead kernel):
    // x = which(4)*colblk(4), y = 8192/256 = 32 -> 512 blocks
    MMArgs qa;
    qa.Bt[0] = Wqt; qa.Bt[1] = Wkt; qa.Bt[2] = Wvt; qa.Bt[3] = Wgt;
    qa.C[0] = Qb;   qa.C[1] = Kb;   qa.C[2] = Vt;   qa.C[3] = Gb;
    qa.C2[0] = nullptr; qa.C2[1] = Ktb; qa.C2[2] = nullptr; qa.C2[3] = nullptr;
    qa.emode[0] = 1; qa.emode[1] = 6; qa.emode[2] = 5; qa.emode[3] = 3;
    mm8_kernel<<<dim3(16, 32), 512, 0, stream>>>(Xb, qa, tbl);

    // chunked-recurrent retention: local states -> scan -> per-chunk output
    state_kernel<<<dim3(32, 32), 256, 0, stream>>>(Ktb, Vt, Sb, gp);
    scan_kernel<<<dim3(8, 32), 256, 0, stream>>>(Sb, gp);
    ret2_kernel<<<dim3(32, 32), 256, 0, stream>>>(Qb, Kb, Vt, Sb, Gb,
                                                  gnw, gnb, Zb, gp);

    MMArgs oa;
    oa.Bt[0] = Wot; oa.Bt[1] = Wot; oa.Bt[2] = Wot; oa.Bt[3] = Wot;
    oa.C[0] = out;  oa.C[1] = out;  oa.C[2] = out;  oa.C[3] = out;
    oa.C2[0] = nullptr; oa.C2[1] = nullptr; oa.C2[2] = nullptr; oa.C2[3] = nullptr;
    oa.emode[0] = 4; oa.emode[1] = 4; oa.emode[2] = 4; oa.emode[3] = 4;
    mm_kernel<<<dim3(8, 64), 256, 0, stream>>>(Zb, oa, tbl);
}

// Round 8
// 367.815 us; speedup vs baseline: 1.0997x; 1.0990x over previous
//
#include <hip/hip_runtime.h>
#include <cmath>

#define BB 4
#define LL 2048
#define DD 1024
#define HH 8
#define MM (BB * LL)   // 8192 rows

struct Gammas { float lg2[8]; };
struct MMArgs { const ushort* Bt[4]; void* C[4]; void* C2[4]; int emode[4]; };

typedef __attribute__((ext_vector_type(8))) short bf16x8;
typedef __attribute__((ext_vector_type(4))) float f32x4;

__device__ __forceinline__ ushort f2bf(float f) {
    uint u = __builtin_bit_cast(uint, f);
    uint r = (u + 0x7fffu + ((u >> 16) & 1u)) >> 16;
    return (ushort)r;
}
__device__ __forceinline__ float bf2f(ushort h) {
    uint u = ((uint)h) << 16;
    return __builtin_bit_cast(float, u);
}
__device__ __forceinline__ void gload16(const void* g, void* l) {
    __builtin_amdgcn_global_load_lds((const __attribute__((address_space(1))) void*)g,
                                     (__attribute__((address_space(3))) void*)l, 16, 0, 0);
}

// ---------------------------------------------------------------------------
// xpos table: tbl[l*64 + i] = {cos*scale, sin*scale, cos/scale, sin/scale}
// ---------------------------------------------------------------------------
__global__ void xpos_table_kernel(float4* __restrict__ tbl) {
    int tid = blockIdx.x * blockDim.x + threadIdx.x;
    if (tid >= LL * 64) return;
    int l = tid >> 6, i = tid & 63;
    float inv = powf(10000.0f, -(float)i / 64.0f);
    float ang = (float)l * inv;
    float s = sinf(ang), c = cosf(ang);
    float base = (2.0f * (float)i + 51.2f) / 179.2f;
    float sc = powf(base, (float)l / 512.0f);
    tbl[tid] = make_float4(c * sc, s * sc, c / sc, s / sc);
}

__global__ __launch_bounds__(256) void cast_kernel(const float* __restrict__ X,
                                                   ushort* __restrict__ Xb) {
    int i = (blockIdx.x * 256 + threadIdx.x) * 4;
    float4 v = *(const float4*)&X[i];
    ushort4 o;
    o.x = f2bf(v.x); o.y = f2bf(v.y); o.z = f2bf(v.z); o.w = f2bf(v.w);
    *(ushort4*)&Xb[i] = o;
}

// ---------------------------------------------------------------------------
// Weight transpose+cast: W[k][n] (flat or per-head (h,d,e)) -> Wt[n][k] bf16
// ---------------------------------------------------------------------------
__global__ __launch_bounds__(256) void wtrans_kernel(const float* __restrict__ W,
                                                     ushort* __restrict__ Wt, int perhead) {
    __shared__ float T[64][68];
    const int k0 = blockIdx.y * 64, n0 = blockIdx.x * 64;
    const int t = threadIdx.x;
    for (int f = t; f < 64 * 16; f += 256) {
        int kk = f >> 4, s = f & 15;
        int n = n0 + s * 4;
        size_t src = perhead ? (size_t)(n >> 7) * 131072 + (size_t)(k0 + kk) * 128 + (n & 127)
                             : (size_t)(k0 + kk) * 1024 + n;
        *(float4*)&T[kk][s * 4] = *(const float4*)&W[src];
    }
    __syncthreads();
    for (int f = t; f < 64 * 8; f += 256) {
        int n = f >> 3, s = f & 7;
        __align__(16) ushort tmp[8];
        #pragma unroll
        for (int j = 0; j < 8; j++) tmp[j] = f2bf(T[s * 8 + j][n]);
        *(uint4*)&Wt[(size_t)(n0 + n) * 1024 + k0 + s * 8] = *(uint4*)tmp;
    }
}

// ---------------------------------------------------------------------------
// bf16 MFMA GEMM (proven config): 128x128 tile, BK=32, 2-phase double-
// buffered LDS, one __syncthreads per K-step.
// __launch_bounds__(256, 4): total regs (arch VGPR + 64 acc) were 132 — 4
// over the 128-reg occupancy cliff (2 waves/SIMD). Forcing the 128 budget
// doubles co-residency to 4 blocks/CU; at K=1024 the per-step cost is
// exposed load latency / residency, so this is the binding constraint.
// LDS 32KB x 4 blocks = 128KB <= 160KB.
// emode: 1 xpos up->bf16, 2 xpos down->bf16, 3 silu->bf16, 4 plain->fp32,
//        5 V-transposed store (Vt[b][v][l]), 6 xpos down -> row-major Kb AND
//        transposed K~t (C2).
// ---------------------------------------------------------------------------
__global__ __launch_bounds__(256, 4) void mm_kernel(
    const ushort* __restrict__ A, MMArgs args, const float4* __restrict__ tbl)
{
    __shared__ __align__(16) ushort As[2][128 * 32];
    __shared__ __align__(16) ushort Bs[2][128 * 32];
    const int t = threadIdx.x;
    const int w = t >> 6, lane = t & 63;
    const int ln = lane & 15, quad = lane >> 4;
    const int which = blockIdx.x >> 3;
    const ushort* Bt = args.Bt[which];
    void* Cv = args.C[which];
    void* Cv2 = args.C2[which];
    const int emode = args.emode[which];
    const int n0 = (blockIdx.x & 7) * 128, m0 = blockIdx.y * 128;
    const int wm = w & 1, wn = w >> 1;

    f32x4 acc[4][4];
    const f32x4 fzero = {0.f, 0.f, 0.f, 0.f};
    #pragma unroll
    for (int i = 0; i < 4; i++)
        #pragma unroll
        for (int j = 0; j < 4; j++) acc[i][j] = fzero;

    const int srow = w * 32 + (lane >> 2);
    const int scol = (lane & 3) * 8;
    const ushort* ga  = A  + (size_t)(m0 + srow) * 1024 + scol;
    const ushort* ga2 = ga + 16 * 1024;
    const ushort* gb  = Bt + (size_t)(n0 + srow) * 1024 + scol;
    const ushort* gb2 = gb + 16 * 1024;
    const int lo1 = (w * 32) * 32;
    const int lo2 = (w * 32 + 16) * 32;

    gload16(ga, &As[0][lo1]);
    gload16(ga2, &As[0][lo2]);
    gload16(gb, &Bs[0][lo1]);
    gload16(gb2, &Bs[0][lo2]);
    __syncthreads();

    for (int kt = 0; kt < 1024; kt += 32) {
        const int cur = (kt >> 5) & 1;
        if (kt < 1024 - 32) {
            const int nk = kt + 32;
            gload16(ga + nk, &As[cur ^ 1][lo1]);
            gload16(ga2 + nk, &As[cur ^ 1][lo2]);
            gload16(gb + nk, &Bs[cur ^ 1][lo1]);
            gload16(gb2 + nk, &Bs[cur ^ 1][lo2]);
        }
        bf16x8 am[4], bn[4];
        #pragma unroll
        for (int i = 0; i < 4; i++)
            am[i] = *(const bf16x8*)&As[cur][(wm * 64 + i * 16 + ln) * 32 + quad * 8];
        #pragma unroll
        for (int i = 0; i < 4; i++)
            bn[i] = *(const bf16x8*)&Bs[cur][(wn * 64 + i * 16 + ln) * 32 + quad * 8];
        #pragma unroll
        for (int mi = 0; mi < 4; mi++)
            #pragma unroll
            for (int ni = 0; ni < 4; ni++)
                acc[mi][ni] = __builtin_amdgcn_mfma_f32_16x16x32_bf16(
                    am[mi], bn[ni], acc[mi][ni], 0, 0, 0);
        __syncthreads();
    }

    #pragma unroll
    for (int mi = 0; mi < 4; mi++) {
        #pragma unroll
        for (int ni = 0; ni < 4; ni++) {
            const int row0 = m0 + wm * 64 + mi * 16 + quad * 4;
            const int e = wn * 64 + ni * 16 + ln;       // col within head
            const int col = n0 + e;
            if (emode == 5) {
                const int b = row0 >> 11, l0 = row0 & (LL - 1);
                ushort4 pk;
                pk.x = f2bf(acc[mi][ni][0]); pk.y = f2bf(acc[mi][ni][1]);
                pk.z = f2bf(acc[mi][ni][2]); pk.w = f2bf(acc[mi][ni][3]);
                *(ushort4*)&((ushort*)Cv)[((size_t)(b * 1024 + col)) * 2048 + l0] = pk;
                continue;
            }
            float vv[4];
            #pragma unroll
            for (int r = 0; r < 4; r++) {
                float v = acc[mi][ni][r];
                if (emode == 1 || emode == 2 || emode == 6) {
                    float4 tt = tbl[(size_t)((row0 + r) & (LL - 1)) * 64 + (e >> 1)];
                    float cc = (emode == 1) ? tt.x : tt.z;
                    float ss = (emode == 1) ? tt.y : tt.w;
                    float partner = __shfl_xor(v, 1);
                    float rot = (e & 1) ? partner : -partner;
                    v = v * cc + rot * ss;
                } else if (emode == 3) {
                    v = v / (1.0f + expf(-v));
                }
                vv[r] = v;
                if (emode == 4)
                    ((float*)Cv)[(size_t)(row0 + r) * 1024 + col] = v;
                else
                    ((ushort*)Cv)[(size_t)(row0 + r) * 1024 + col] = f2bf(v);
            }
            if (emode == 6) {
                const int b = row0 >> 11, l0 = row0 & (LL - 1);
                ushort4 pk;
                pk.x = f2bf(vv[0]); pk.y = f2bf(vv[1]);
                pk.z = f2bf(vv[2]); pk.w = f2bf(vv[3]);
                *(ushort4*)&((ushort*)Cv2)[((size_t)(b * 1024 + col)) * 2048 + l0] = pk;
            }
        }
    }
}

// ---------------------------------------------------------------------------
// R1: per-chunk local state L_c^T[v][d] = sum_m gamma^{63-m} K~[m][d] V[m][v],
// one block per (bh, c). MFMA over m (k=64), LDS-bounced coalesced bf16 store.
// ---------------------------------------------------------------------------
__global__ __launch_bounds__(256) void state_kernel(
    const ushort* __restrict__ Ktb, const ushort* __restrict__ Vt,
    ushort* __restrict__ Sb, Gammas gp)
{
    __shared__ __align__(16) ushort shbuf[2 * 128 * 72];   // Ktl | Vwl, reused as Lsh
    ushort* Ktl = shbuf;
    ushort* Vwl = shbuf + 128 * 72;

    const int t = threadIdx.x;
    const int w = t >> 6, lane = t & 63, ln = lane & 15, quad = lane >> 4;
    const int c = blockIdx.x, bh = blockIdx.y;
    const int b = bh >> 3, h = bh & 7;
    const float lg2 = gp.lg2[h];
    const size_t tbase = ((size_t)b * 1024 + h * 128) * 2048 + (size_t)c * 64;

    const int sr = t >> 1, soff = (t & 1) * 32;
    #pragma unroll
    for (int j = 0; j < 4; j++)
        *(uint4*)&Ktl[sr * 72 + soff + j * 8] =
            *(const uint4*)&Ktb[tbase + (size_t)sr * 2048 + soff + j * 8];
    #pragma unroll
    for (int j = 0; j < 4; j++) {
        uint4 raw = *(const uint4*)&Vt[tbase + (size_t)sr * 2048 + soff + j * 8];
        ushort* rp = (ushort*)&raw;
        __align__(16) ushort tmp[8];
        #pragma unroll
        for (int jj = 0; jj < 8; jj++) {
            int m = soff + j * 8 + jj;
            tmp[jj] = f2bf(bf2f(rp[jj]) * exp2f(lg2 * (float)(63 - m)));
        }
        *(uint4*)&Vwl[sr * 72 + soff + j * 8] = *(uint4*)tmp;
    }
    __syncthreads();

    const int wm = w & 1, wn = w >> 1;
    f32x4 acc[4][4];
    const f32x4 fzero = {0.f, 0.f, 0.f, 0.f};
    #pragma unroll
    for (int i = 0; i < 4; i++)
        #pragma unroll
        for (int j = 0; j < 4; j++) acc[i][j] = fzero;

    #pragma unroll
    for (int ks = 0; ks < 2; ks++) {
        bf16x8 am[4], bn[4];
        #pragma unroll
        for (int mi = 0; mi < 4; mi++)
            am[mi] = *(const bf16x8*)&Ktl[(wm * 64 + mi * 16 + ln) * 72 + ks * 32 + quad * 8];
        #pragma unroll
        for (int ni = 0; ni < 4; ni++)
            bn[ni] = *(const bf16x8*)&Vwl[(wn * 64 + ni * 16 + ln) * 72 + ks * 32 + quad * 8];
        #pragma unroll
        for (int mi = 0; mi < 4; mi++)
            #pragma unroll
            for (int ni = 0; ni < 4; ni++)
                acc[mi][ni] = __builtin_amdgcn_mfma_f32_16x16x32_bf16(
                    am[mi], bn[ni], acc[mi][ni], 0, 0, 0);
    }
    __syncthreads();

    ushort* Lsh = shbuf;
    #pragma unroll
    for (int mi = 0; mi < 4; mi++) {
        #pragma unroll
        for (int ni = 0; ni < 4; ni++) {
            const int d0 = wm * 64 + mi * 16 + quad * 4;
            const int v = wn * 64 + ni * 16 + ln;
            ushort4 pk;
            pk.x = f2bf(acc[mi][ni][0]); pk.y = f2bf(acc[mi][ni][1]);
            pk.z = f2bf(acc[mi][ni][2]); pk.w = f2bf(acc[mi][ni][3]);
            *(ushort4*)&Lsh[v * 136 + d0] = pk;
        }
    }
    __syncthreads();
    ushort* dst = Sb + (size_t)(bh * 32 + c) * 128 * 128;
    const int orow = t >> 1, ooff = (t & 1) * 64;
    #pragma unroll
    for (int j = 0; j < 8; j++)
        *(uint4*)&dst[(size_t)orow * 128 + ooff + j * 8] =
            *(uint4*)&Lsh[orow * 136 + ooff + j * 8];
}

// ---------------------------------------------------------------------------
// R2: in-place scan over chunks: slot c-1 <- P_c = g64*P_{c-1} + L_{c-1}.
// ---------------------------------------------------------------------------
__global__ __launch_bounds__(256) void scan_kernel(ushort* __restrict__ Sb, Gammas gp)
{
    const int t = threadIdx.x;
    const int vb = blockIdx.x, bh = blockIdx.y;
    const int h = bh & 7;
    const float g64 = exp2f(64.0f * gp.lg2[h]);
    const int v = vb * 16 + (t >> 4);
    const int d0 = (t & 15) * 8;

    float acc[8];
    #pragma unroll
    for (int j = 0; j < 8; j++) acc[j] = 0.f;

    for (int c = 1; c < 32; c++) {
        ushort* p = Sb + ((size_t)(bh * 32 + (c - 1)) * 128 + v) * 128 + d0;
        uint4 lv = *(const uint4*)p;
        ushort* lp = (ushort*)&lv;
        __align__(16) ushort o[8];
        #pragma unroll
        for (int j = 0; j < 8; j++) {
            acc[j] = g64 * acc[j] + bf2f(lp[j]);
            o[j] = f2bf(acc[j]);
        }
        *(uint4*)p = *(uint4*)o;
    }
}

// ---------------------------------------------------------------------------
// R3: Y(chunk c) = gamma^{r+1} * Q~ . P_c  +  intra-chunk retention,
// fused GroupNorm + affine + silu-gate epilogue. One block per (bh, c).
// ---------------------------------------------------------------------------
__global__ __launch_bounds__(256) void ret2_kernel(
    const ushort* __restrict__ Qb, const ushort* __restrict__ Kb,
    const ushort* __restrict__ Vt, const ushort* __restrict__ Pt,
    const ushort* __restrict__ Gb,
    const float* __restrict__ gnw, const float* __restrict__ gnb,
    ushort* __restrict__ Z, Gammas gp)
{
    __shared__ __align__(16) ushort Ks[64 * 136];
    __shared__ __align__(16) ushort Vs[128 * 72];
    __shared__ __align__(16) ushort Ss[64 * 72];
    __shared__ __align__(16) ushort Ps[128 * 136];

    const int t = threadIdx.x;
    const int w = t >> 6, lane = t & 63, ln = lane & 15, quad = lane >> 4;
    const int c = blockIdx.x, bh = blockIdx.y;
    const int b = bh >> 3, h = bh & 7;
    const float lg2 = gp.lg2[h];
    const size_t qkbase = (size_t)b * LL * 1024 + (size_t)h * 128;
    const size_t vtbase = ((size_t)b * 1024 + h * 128) * 2048;
    const int n0 = c * 64;

    float dmk[4], drr[4];
    #pragma unroll
    for (int kt = 0; kt < 4; kt++)
        dmk[kt] = exp2f(-(float)(kt * 16 + quad * 4) * lg2);
    #pragma unroll
    for (int r = 0; r < 4; r++)
        drr[r] = exp2f(-(float)r * lg2);

    float gwv[8], gbv[8];
    #pragma unroll
    for (int vt = 0; vt < 8; vt++) {
        gwv[vt] = gnw[h * 128 + vt * 16 + ln];
        gbv[vt] = gnb[h * 128 + vt * 16 + ln];
    }

    const int krow = t >> 4, kc = (t & 15) * 8;
    const int vrow = t >> 3, vc = (t & 7) * 8;
    #pragma unroll
    for (int i = 0; i < 4; i++)
        *(uint4*)&Ks[(krow + i * 16) * 136 + kc] =
            *(const uint4*)&Kb[qkbase + (size_t)(n0 + krow + i * 16) * 1024 + kc];
    #pragma unroll
    for (int i = 0; i < 4; i++)
        *(uint4*)&Vs[(vrow + i * 32) * 72 + vc] =
            *(const uint4*)&Vt[vtbase + (size_t)(vrow + i * 32) * 2048 + n0 + vc];
    if (c > 0) {
        const ushort* psrc = Pt + (size_t)(bh * 32 + (c - 1)) * 128 * 128;
        const int pr = t >> 1, poff = (t & 1) * 64;
        #pragma unroll
        for (int j = 0; j < 8; j++)
            *(uint4*)&Ps[pr * 136 + poff + j * 8] =
                *(const uint4*)&psrc[(size_t)pr * 128 + poff + j * 8];
    }

    bf16x8 aq[4];
    #pragma unroll
    for (int ks = 0; ks < 4; ks++)
        aq[ks] = *(const bf16x8*)&Qb[qkbase + (size_t)(n0 + 16 * w + ln) * 1024
                                     + ks * 32 + quad * 8];
    f32x4 y[8];
    const f32x4 fzero = {0.f, 0.f, 0.f, 0.f};
    #pragma unroll
    for (int vt = 0; vt < 8; vt++) y[vt] = fzero;

    __syncthreads();

    if (c > 0) {
        #pragma unroll
        for (int ks = 0; ks < 4; ks++) {
            #pragma unroll
            for (int vt = 0; vt < 8; vt++) {
                bf16x8 bp = *(const bf16x8*)&Ps[(vt * 16 + ln) * 136 + ks * 32 + quad * 8];
                y[vt] = __builtin_amdgcn_mfma_f32_16x16x32_bf16(aq[ks], bp, y[vt], 0, 0, 0);
            }
        }
        #pragma unroll
        for (int rr = 0; rr < 4; rr++) {
            const float sc = exp2f(lg2 * (float)(16 * w + quad * 4 + rr + 1));
            #pragma unroll
            for (int vt = 0; vt < 8; vt++) y[vt][rr] *= sc;
        }
    }

    f32x4 s4[4];
    #pragma unroll
    for (int kt = 0; kt < 4; kt++) s4[kt] = fzero;
    #pragma unroll
    for (int ks = 0; ks < 4; ks++) {
        #pragma unroll
        for (int kt = 0; kt < 4; kt++) {
            bf16x8 bk = *(const bf16x8*)&Ks[(kt * 16 + ln) * 136 + ks * 32 + quad * 8];
            s4[kt] = __builtin_amdgcn_mfma_f32_16x16x32_bf16(bk, aq[ks], s4[kt], 0, 0, 0);
        }
    }
    const float dq = exp2f((float)(16 * w + ln) * lg2);
    #pragma unroll
    for (int kt = 0; kt < 4; kt++) {
        const float db = dq * dmk[kt];
        ushort4 pk;
        pk.x = f2bf((kt * 16 + quad * 4 + 0 <= 16 * w + ln) ? s4[kt][0] * db * drr[0] : 0.f);
        pk.y = f2bf((kt * 16 + quad * 4 + 1 <= 16 * w + ln) ? s4[kt][1] * db * drr[1] : 0.f);
        pk.z = f2bf((kt * 16 + quad * 4 + 2 <= 16 * w + ln) ? s4[kt][2] * db * drr[2] : 0.f);
        pk.w = f2bf((kt * 16 + quad * 4 + 3 <= 16 * w + ln) ? s4[kt][3] * db * drr[3] : 0.f);
        *(ushort4*)&Ss[(16 * w + ln) * 72 + kt * 16 + quad * 4] = pk;
    }
    #pragma unroll
    for (int ks2 = 0; ks2 < 2; ks2++) {
        bf16x8 as = *(const bf16x8*)&Ss[(16 * w + ln) * 72 + ks2 * 32 + quad * 8];
        #pragma unroll
        for (int vt = 0; vt < 8; vt++) {
            bf16x8 bv = *(const bf16x8*)&Vs[(vt * 16 + ln) * 72 + ks2 * 32 + quad * 8];
            y[vt] = __builtin_amdgcn_mfma_f32_16x16x32_bf16(as, bv, y[vt], 0, 0, 0);
        }
    }

    #pragma unroll
    for (int r = 0; r < 4; r++) {
        float s = 0.f, sq = 0.f;
        #pragma unroll
        for (int vt = 0; vt < 8; vt++) {
            float v = y[vt][r];
            s += v; sq += v * v;
        }
        #pragma unroll
        for (int off = 8; off >= 1; off >>= 1) {
            s  += __shfl_xor(s, off, 64);
            sq += __shfl_xor(sq, off, 64);
        }
        float mean = s * 0.0078125f;
        float var = sq * 0.0078125f - mean * mean;
        float rstd = rsqrtf(var + 1e-5f);
        const size_t row = (size_t)(b * LL + n0 + 16 * w + quad * 4 + r);
        #pragma unroll
        for (int vt = 0; vt < 8; vt++) {
            float gv = bf2f(Gb[row * 1024 + h * 128 + vt * 16 + ln]);
            float o = (y[vt][r] - mean) * rstd * gwv[vt] + gbv[vt];
            Z[row * 1024 + h * 128 + vt * 16 + ln] = f2bf(o * gv);
        }
    }
}

// ---------------------------------------------------------------------------
extern "C" void kernel_launch(void* const* d_in, const int* in_sizes, int n_in,
                              void* d_out, int out_size, void* d_ws, size_t ws_size,
                              hipStream_t stream) {
    const float* X   = (const float*)d_in[0];
    const float* Wq  = (const float*)d_in[1];
    const float* Wk  = (const float*)d_in[2];
    const float* Wv  = (const float*)d_in[3];
    const float* Wg  = (const float*)d_in[4];
    const float* Wo  = (const float*)d_in[5];
    const float* gnw = (const float*)d_in[6];
    const float* gnb = (const float*)d_in[7];
    float* out = (float*)d_out;

    const size_t MB = 1u << 20;
    char* base = (char*)d_ws;
    // Sb (32 MB, 0-32) overlays tbl/Xb/Wq..Wg, which die after the QKVG mm.
    ushort* Sb  = (ushort*)base;                        // 0-32  (L then P, bf16)
    float4* tbl = (float4*)base;                        // 0-2
    ushort* Xb  = (ushort*)(base + 2 * MB);             // 2-18
    ushort* Wqt = (ushort*)(base + 18 * MB);
    ushort* Wkt = (ushort*)(base + 20 * MB);
    ushort* Wvt = (ushort*)(base + 22 * MB);
    ushort* Wgt = (ushort*)(base + 24 * MB);
    ushort* Wot = (ushort*)(base + 32 * MB);            // 32-34
    ushort* Qb  = (ushort*)(base + 34 * MB);            // 34-50
    ushort* Kb  = (ushort*)(base + 50 * MB);            // 50-66
    ushort* Gb  = (ushort*)(base + 66 * MB);            // 66-82
    ushort* Vt  = (ushort*)(base + 82 * MB);            // 82-98
    ushort* Ktb = (ushort*)(base + 98 * MB);            // 98-114 (dead after R1)
    ushort* Zb  = (ushort*)(base + 98 * MB);            // reuses Ktb region in R3+

    Gammas gp;
    for (int h = 0; h < 8; h++) {
        double lin = log(1.0 / 32.0) +
                     (log(1.0 / 512.0) - log(1.0 / 32.0)) * (double)h / 7.0;
        float gamma = 1.0f - expf((float)lin);
        gp.lg2[h] = log2f(gamma);
    }

    xpos_table_kernel<<<(LL * 64) / 256, 256, 0, stream>>>(tbl);
    cast_kernel<<<MM * 1024 / 1024, 256, 0, stream>>>(X, Xb);

    dim3 wgrid(16, 16);
    wtrans_kernel<<<wgrid, 256, 0, stream>>>(Wq, Wqt, 1);
    wtrans_kernel<<<wgrid, 256, 0, stream>>>(Wk, Wkt, 1);
    wtrans_kernel<<<wgrid, 256, 0, stream>>>(Wv, Wvt, 1);
    wtrans_kernel<<<wgrid, 256, 0, stream>>>(Wg, Wgt, 0);
    wtrans_kernel<<<wgrid, 256, 0, stream>>>(Wo, Wot, 0);

    // fused Q/K/V/G projections; K emits row-major Kb AND transposed K~t
    MMArgs qa;
    qa.Bt[0] = Wqt; qa.Bt[1] = Wkt; qa.Bt[2] = Wvt; qa.Bt[3] = Wgt;
    qa.C[0] = Qb;   qa.C[1] = Kb;   qa.C[2] = Vt;   qa.C[3] = Gb;
    qa.C2[0] = nullptr; qa.C2[1] = Ktb; qa.C2[2] = nullptr; qa.C2[3] = nullptr;
    qa.emode[0] = 1; qa.emode[1] = 6; qa.emode[2] = 5; qa.emode[3] = 3;
    mm_kernel<<<dim3(32, 64), 256, 0, stream>>>(Xb, qa, tbl);

    // chunked-recurrent retention: local states -> scan -> per-chunk output
    state_kernel<<<dim3(32, 32), 256, 0, stream>>>(Ktb, Vt, Sb, gp);
    scan_kernel<<<dim3(8, 32), 256, 0, stream>>>(Sb, gp);
    ret2_kernel<<<dim3(32, 32), 256, 0, stream>>>(Qb, Kb, Vt, Sb, Gb,
                                                  gnw, gnb, Zb, gp);

    MMArgs oa;
    oa.Bt[0] = Wot; oa.Bt[1] = Wot; oa.Bt[2] = Wot; oa.Bt[3] = Wot;
    oa.C[0] = out;  oa.C[1] = out;  oa.C[2] = out;  oa.C[3] = out;
    oa.C2[0] = nullptr; oa.C2[1] = nullptr; oa.C2[2] = nullptr; oa.C2[3] = nullptr;
    oa.emode[0] = 4; oa.emode[1] = 4; oa.emode[2] = 4; oa.emode[3] = 4;
    mm_kernel<<<dim3(8, 64), 256, 0, stream>>>(Zb, oa, tbl);
}

// Round 9
// 363.780 us; speedup vs baseline: 1.1119x; 1.0111x over previous
//
#include <hip/hip_runtime.h>
#include <cmath>

#define BB 4
#define LL 2048
#define DD 1024
#define HH 8
#define MM (BB * LL)   // 8192 rows

struct Gammas { float lg2[8]; };
struct MMArgs { const ushort* Bt[4]; void* C[4]; void* C2[4]; int emode[4]; };
struct PrepArgs { const float* W[5]; ushort* Wt[5]; int perhead[5]; };

typedef __attribute__((ext_vector_type(8))) short bf16x8;
typedef __attribute__((ext_vector_type(4))) float f32x4;

__device__ __forceinline__ ushort f2bf(float f) {
    uint u = __builtin_bit_cast(uint, f);
    uint r = (u + 0x7fffu + ((u >> 16) & 1u)) >> 16;
    return (ushort)r;
}
__device__ __forceinline__ float bf2f(ushort h) {
    uint u = ((uint)h) << 16;
    return __builtin_bit_cast(float, u);
}
__device__ __forceinline__ void gload16(const void* g, void* l) {
    __builtin_amdgcn_global_load_lds((const __attribute__((address_space(1))) void*)g,
                                     (__attribute__((address_space(3))) void*)l, 16, 0, 0);
}

// ---------------------------------------------------------------------------
// prep: ONE launch for xpos table + X cast + all 5 weight transposes.
// blocks [0,512): tbl ; [512,8704): cast ; [8704,9984): wtrans (5 x 256).
// ---------------------------------------------------------------------------
__global__ __launch_bounds__(256) void prep_kernel(
    const float* __restrict__ X, ushort* __restrict__ Xb,
    float4* __restrict__ tbl, PrepArgs pa)
{
    __shared__ float T[64][68];
    const int blk = blockIdx.x;
    const int t = threadIdx.x;

    if (blk < 512) {
        // xpos table: tbl[l*64+i] = {cos*sc, sin*sc, cos/sc, sin/sc}
        int tid = blk * 256 + t;
        int l = tid >> 6, i = tid & 63;
        float inv = powf(10000.0f, -(float)i / 64.0f);
        float ang = (float)l * inv;
        float s = sinf(ang), c = cosf(ang);
        float base = (2.0f * (float)i + 51.2f) / 179.2f;
        float sc = powf(base, (float)l / 512.0f);
        tbl[tid] = make_float4(c * sc, s * sc, c / sc, s / sc);
        return;
    }
    if (blk < 8704) {
        int i = ((blk - 512) * 256 + t) * 4;
        float4 v = *(const float4*)&X[i];
        ushort4 o;
        o.x = f2bf(v.x); o.y = f2bf(v.y); o.z = f2bf(v.z); o.w = f2bf(v.w);
        *(ushort4*)&Xb[i] = o;
        return;
    }
    // weight transpose+cast: W[k][n] (flat or per-head) -> Wt[n][k] bf16
    const int wblk = blk - 8704;
    const int widx = wblk >> 8;              // 0..4
    const int sub = wblk & 255;
    const float* W = pa.W[widx];
    ushort* Wt = pa.Wt[widx];
    const int perhead = pa.perhead[widx];
    const int k0 = (sub >> 4) * 64, n0 = (sub & 15) * 64;
    for (int f = t; f < 64 * 16; f += 256) {
        int kk = f >> 4, s = f & 15;
        int n = n0 + s * 4;
        size_t src = perhead ? (size_t)(n >> 7) * 131072 + (size_t)(k0 + kk) * 128 + (n & 127)
                             : (size_t)(k0 + kk) * 1024 + n;
        *(float4*)&T[kk][s * 4] = *(const float4*)&W[src];
    }
    __syncthreads();
    for (int f = t; f < 64 * 8; f += 256) {
        int n = f >> 3, s = f & 7;
        __align__(16) ushort tmp[8];
        #pragma unroll
        for (int j = 0; j < 8; j++) tmp[j] = f2bf(T[s * 8 + j][n]);
        *(uint4*)&Wt[(size_t)(n0 + n) * 1024 + k0 + s * 8] = *(uint4*)tmp;
    }
}

// ---------------------------------------------------------------------------
// bf16 MFMA GEMM (proven config): 128x128 tile, BK=32, 2-phase double-
// buffered LDS, one __syncthreads per K-step. __launch_bounds__(256,4)
// keeps total regs <= 128 (4 blocks/CU; LDS 32KB x 4 = 128KB).
// emode: 1 xpos up->bf16, 2 xpos down->bf16, 3 silu->bf16, 4 plain->fp32,
//        5 V-transposed store (Vt[b][v][l]), 6 xpos down -> row-major Kb AND
//        transposed K~t (C2).
// ---------------------------------------------------------------------------
__global__ __launch_bounds__(256, 4) void mm_kernel(
    const ushort* __restrict__ A, MMArgs args, const float4* __restrict__ tbl)
{
    __shared__ __align__(16) ushort As[2][128 * 32];
    __shared__ __align__(16) ushort Bs[2][128 * 32];
    const int t = threadIdx.x;
    const int w = t >> 6, lane = t & 63;
    const int ln = lane & 15, quad = lane >> 4;
    const int which = blockIdx.x >> 3;
    const ushort* Bt = args.Bt[which];
    void* Cv = args.C[which];
    void* Cv2 = args.C2[which];
    const int emode = args.emode[which];
    const int n0 = (blockIdx.x & 7) * 128, m0 = blockIdx.y * 128;
    const int wm = w & 1, wn = w >> 1;

    f32x4 acc[4][4];
    const f32x4 fzero = {0.f, 0.f, 0.f, 0.f};
    #pragma unroll
    for (int i = 0; i < 4; i++)
        #pragma unroll
        for (int j = 0; j < 4; j++) acc[i][j] = fzero;

    const int srow = w * 32 + (lane >> 2);
    const int scol = (lane & 3) * 8;
    const ushort* ga  = A  + (size_t)(m0 + srow) * 1024 + scol;
    const ushort* ga2 = ga + 16 * 1024;
    const ushort* gb  = Bt + (size_t)(n0 + srow) * 1024 + scol;
    const ushort* gb2 = gb + 16 * 1024;
    const int lo1 = (w * 32) * 32;
    const int lo2 = (w * 32 + 16) * 32;

    gload16(ga, &As[0][lo1]);
    gload16(ga2, &As[0][lo2]);
    gload16(gb, &Bs[0][lo1]);
    gload16(gb2, &Bs[0][lo2]);
    __syncthreads();

    for (int kt = 0; kt < 1024; kt += 32) {
        const int cur = (kt >> 5) & 1;
        if (kt < 1024 - 32) {
            const int nk = kt + 32;
            gload16(ga + nk, &As[cur ^ 1][lo1]);
            gload16(ga2 + nk, &As[cur ^ 1][lo2]);
            gload16(gb + nk, &Bs[cur ^ 1][lo1]);
            gload16(gb2 + nk, &Bs[cur ^ 1][lo2]);
        }
        bf16x8 am[4], bn[4];
        #pragma unroll
        for (int i = 0; i < 4; i++)
            am[i] = *(const bf16x8*)&As[cur][(wm * 64 + i * 16 + ln) * 32 + quad * 8];
        #pragma unroll
        for (int i = 0; i < 4; i++)
            bn[i] = *(const bf16x8*)&Bs[cur][(wn * 64 + i * 16 + ln) * 32 + quad * 8];
        #pragma unroll
        for (int mi = 0; mi < 4; mi++)
            #pragma unroll
            for (int ni = 0; ni < 4; ni++)
                acc[mi][ni] = __builtin_amdgcn_mfma_f32_16x16x32_bf16(
                    am[mi], bn[ni], acc[mi][ni], 0, 0, 0);
        __syncthreads();
    }

    #pragma unroll
    for (int mi = 0; mi < 4; mi++) {
        #pragma unroll
        for (int ni = 0; ni < 4; ni++) {
            const int row0 = m0 + wm * 64 + mi * 16 + quad * 4;
            const int e = wn * 64 + ni * 16 + ln;       // col within head
            const int col = n0 + e;
            if (emode == 5) {
                const int b = row0 >> 11, l0 = row0 & (LL - 1);
                ushort4 pk;
                pk.x = f2bf(acc[mi][ni][0]); pk.y = f2bf(acc[mi][ni][1]);
                pk.z = f2bf(acc[mi][ni][2]); pk.w = f2bf(acc[mi][ni][3]);
                *(ushort4*)&((ushort*)Cv)[((size_t)(b * 1024 + col)) * 2048 + l0] = pk;
                continue;
            }
            float vv[4];
            #pragma unroll
            for (int r = 0; r < 4; r++) {
                float v = acc[mi][ni][r];
                if (emode == 1 || emode == 2 || emode == 6) {
                    float4 tt = tbl[(size_t)((row0 + r) & (LL - 1)) * 64 + (e >> 1)];
                    float cc = (emode == 1) ? tt.x : tt.z;
                    float ss = (emode == 1) ? tt.y : tt.w;
                    float partner = __shfl_xor(v, 1);
                    float rot = (e & 1) ? partner : -partner;
                    v = v * cc + rot * ss;
                } else if (emode == 3) {
                    v = v / (1.0f + expf(-v));
                }
                vv[r] = v;
                if (emode == 4)
                    ((float*)Cv)[(size_t)(row0 + r) * 1024 + col] = v;
                else
                    ((ushort*)Cv)[(size_t)(row0 + r) * 1024 + col] = f2bf(v);
            }
            if (emode == 6) {
                const int b = row0 >> 11, l0 = row0 & (LL - 1);
                ushort4 pk;
                pk.x = f2bf(vv[0]); pk.y = f2bf(vv[1]);
                pk.z = f2bf(vv[2]); pk.w = f2bf(vv[3]);
                *(ushort4*)&((ushort*)Cv2)[((size_t)(b * 1024 + col)) * 2048 + l0] = pk;
            }
        }
    }
}

// ---------------------------------------------------------------------------
// R1: per-chunk local state L_c^T[v][d] = sum_m gamma^{63-m} K~[m][d] V[m][v],
// one block per (bh, c). MFMA over m (k=64), LDS-bounced coalesced bf16 store.
// ---------------------------------------------------------------------------
__global__ __launch_bounds__(256) void state_kernel(
    const ushort* __restrict__ Ktb, const ushort* __restrict__ Vt,
    ushort* __restrict__ Sb, Gammas gp)
{
    __shared__ __align__(16) ushort shbuf[2 * 128 * 72];   // Ktl | Vwl, reused as Lsh
    ushort* Ktl = shbuf;
    ushort* Vwl = shbuf + 128 * 72;

    const int t = threadIdx.x;
    const int w = t >> 6, lane = t & 63, ln = lane & 15, quad = lane >> 4;
    const int c = blockIdx.x, bh = blockIdx.y;
    const int b = bh >> 3, h = bh & 7;
    const float lg2 = gp.lg2[h];
    const size_t tbase = ((size_t)b * 1024 + h * 128) * 2048 + (size_t)c * 64;

    const int sr = t >> 1, soff = (t & 1) * 32;
    #pragma unroll
    for (int j = 0; j < 4; j++)
        *(uint4*)&Ktl[sr * 72 + soff + j * 8] =
            *(const uint4*)&Ktb[tbase + (size_t)sr * 2048 + soff + j * 8];
    #pragma unroll
    for (int j = 0; j < 4; j++) {
        uint4 raw = *(const uint4*)&Vt[tbase + (size_t)sr * 2048 + soff + j * 8];
        ushort* rp = (ushort*)&raw;
        __align__(16) ushort tmp[8];
        #pragma unroll
        for (int jj = 0; jj < 8; jj++) {
            int m = soff + j * 8 + jj;
            tmp[jj] = f2bf(bf2f(rp[jj]) * exp2f(lg2 * (float)(63 - m)));
        }
        *(uint4*)&Vwl[sr * 72 + soff + j * 8] = *(uint4*)tmp;
    }
    __syncthreads();

    const int wm = w & 1, wn = w >> 1;
    f32x4 acc[4][4];
    const f32x4 fzero = {0.f, 0.f, 0.f, 0.f};
    #pragma unroll
    for (int i = 0; i < 4; i++)
        #pragma unroll
        for (int j = 0; j < 4; j++) acc[i][j] = fzero;

    #pragma unroll
    for (int ks = 0; ks < 2; ks++) {
        bf16x8 am[4], bn[4];
        #pragma unroll
        for (int mi = 0; mi < 4; mi++)
            am[mi] = *(const bf16x8*)&Ktl[(wm * 64 + mi * 16 + ln) * 72 + ks * 32 + quad * 8];
        #pragma unroll
        for (int ni = 0; ni < 4; ni++)
            bn[ni] = *(const bf16x8*)&Vwl[(wn * 64 + ni * 16 + ln) * 72 + ks * 32 + quad * 8];
        #pragma unroll
        for (int mi = 0; mi < 4; mi++)
            #pragma unroll
            for (int ni = 0; ni < 4; ni++)
                acc[mi][ni] = __builtin_amdgcn_mfma_f32_16x16x32_bf16(
                    am[mi], bn[ni], acc[mi][ni], 0, 0, 0);
    }
    __syncthreads();

    ushort* Lsh = shbuf;
    #pragma unroll
    for (int mi = 0; mi < 4; mi++) {
        #pragma unroll
        for (int ni = 0; ni < 4; ni++) {
            const int d0 = wm * 64 + mi * 16 + quad * 4;
            const int v = wn * 64 + ni * 16 + ln;
            ushort4 pk;
            pk.x = f2bf(acc[mi][ni][0]); pk.y = f2bf(acc[mi][ni][1]);
            pk.z = f2bf(acc[mi][ni][2]); pk.w = f2bf(acc[mi][ni][3]);
            *(ushort4*)&Lsh[v * 136 + d0] = pk;
        }
    }
    __syncthreads();
    ushort* dst = Sb + (size_t)(bh * 32 + c) * 128 * 128;
    const int orow = t >> 1, ooff = (t & 1) * 64;
    #pragma unroll
    for (int j = 0; j < 8; j++)
        *(uint4*)&dst[(size_t)orow * 128 + ooff + j * 8] =
            *(uint4*)&Lsh[orow * 136 + ooff + j * 8];
}

// ---------------------------------------------------------------------------
// R2: in-place scan over chunks: slot c-1 <- P_c = g64*P_{c-1} + L_{c-1}.
// ---------------------------------------------------------------------------
__global__ __launch_bounds__(256) void scan_kernel(ushort* __restrict__ Sb, Gammas gp)
{
    const int t = threadIdx.x;
    const int vb = blockIdx.x, bh = blockIdx.y;
    const int h = bh & 7;
    const float g64 = exp2f(64.0f * gp.lg2[h]);
    const int v = vb * 16 + (t >> 4);
    const int d0 = (t & 15) * 8;

    float acc[8];
    #pragma unroll
    for (int j = 0; j < 8; j++) acc[j] = 0.f;

    for (int c = 1; c < 32; c++) {
        ushort* p = Sb + ((size_t)(bh * 32 + (c - 1)) * 128 + v) * 128 + d0;
        uint4 lv = *(const uint4*)p;
        ushort* lp = (ushort*)&lv;
        __align__(16) ushort o[8];
        #pragma unroll
        for (int j = 0; j < 8; j++) {
            acc[j] = g64 * acc[j] + bf2f(lp[j]);
            o[j] = f2bf(acc[j]);
        }
        *(uint4*)p = *(uint4*)o;
    }
}

// ---------------------------------------------------------------------------
// R3: Y(chunk c) = gamma^{r+1} * Q~ . P_c  +  intra-chunk retention,
// fused GroupNorm + affine + silu-gate epilogue. One block per (bh, c).
// P consumed DIRECTLY global->register (one 16B load per fragment; P has no
// cross-block reuse so LDS staging bought nothing). LDS 80->45KB => 3
// blocks/CU. Inter-chunk MFMA runs BEFORE the barrier, overlapping staging.
// ---------------------------------------------------------------------------
__global__ __launch_bounds__(256) void ret2_kernel(
    const ushort* __restrict__ Qb, const ushort* __restrict__ Kb,
    const ushort* __restrict__ Vt, const ushort* __restrict__ Pt,
    const ushort* __restrict__ Gb,
    const float* __restrict__ gnw, const float* __restrict__ gnb,
    ushort* __restrict__ Z, Gammas gp)
{
    __shared__ __align__(16) ushort Ks[64 * 136];
    __shared__ __align__(16) ushort Vs[128 * 72];
    __shared__ __align__(16) ushort Ss[64 * 72];

    const int t = threadIdx.x;
    const int w = t >> 6, lane = t & 63, ln = lane & 15, quad = lane >> 4;
    const int c = blockIdx.x, bh = blockIdx.y;
    const int b = bh >> 3, h = bh & 7;
    const float lg2 = gp.lg2[h];
    const size_t qkbase = (size_t)b * LL * 1024 + (size_t)h * 128;
    const size_t vtbase = ((size_t)b * 1024 + h * 128) * 2048;
    const int n0 = c * 64;

    float dmk[4], drr[4];
    #pragma unroll
    for (int kt = 0; kt < 4; kt++)
        dmk[kt] = exp2f(-(float)(kt * 16 + quad * 4) * lg2);
    #pragma unroll
    for (int r = 0; r < 4; r++)
        drr[r] = exp2f(-(float)r * lg2);

    float gwv[8], gbv[8];
    #pragma unroll
    for (int vt = 0; vt < 8; vt++) {
        gwv[vt] = gnw[h * 128 + vt * 16 + ln];
        gbv[vt] = gnb[h * 128 + vt * 16 + ln];
    }

    const int krow = t >> 4, kc = (t & 15) * 8;
    const int vrow = t >> 3, vc = (t & 7) * 8;
    #pragma unroll
    for (int i = 0; i < 4; i++)
        *(uint4*)&Ks[(krow + i * 16) * 136 + kc] =
            *(const uint4*)&Kb[qkbase + (size_t)(n0 + krow + i * 16) * 1024 + kc];
    #pragma unroll
    for (int i = 0; i < 4; i++)
        *(uint4*)&Vs[(vrow + i * 32) * 72 + vc] =
            *(const uint4*)&Vt[vtbase + (size_t)(vrow + i * 32) * 2048 + n0 + vc];

    bf16x8 aq[4];
    #pragma unroll
    for (int ks = 0; ks < 4; ks++)
        aq[ks] = *(const bf16x8*)&Qb[qkbase + (size_t)(n0 + 16 * w + ln) * 1024
                                     + ks * 32 + quad * 8];
    f32x4 y[8];
    const f32x4 fzero = {0.f, 0.f, 0.f, 0.f};
    #pragma unroll
    for (int vt = 0; vt < 8; vt++) y[vt] = fzero;

    // inter-chunk: y = Q~ . P_c with P fragments loaded straight from global
    // (8 contiguous bf16 per fragment). Runs before the barrier -> overlaps
    // the K/V LDS staging above.
    if (c > 0) {
        const ushort* psrc = Pt + (size_t)(bh * 32 + (c - 1)) * 128 * 128;
        #pragma unroll
        for (int ks = 0; ks < 4; ks++) {
            bf16x8 bp[8];
            #pragma unroll
            for (int vt = 0; vt < 8; vt++)
                bp[vt] = *(const bf16x8*)&psrc[(size_t)(vt * 16 + ln) * 128
                                               + ks * 32 + quad * 8];
            #pragma unroll
            for (int vt = 0; vt < 8; vt++)
                y[vt] = __builtin_amdgcn_mfma_f32_16x16x32_bf16(aq[ks], bp[vt], y[vt], 0, 0, 0);
        }
        #pragma unroll
        for (int rr = 0; rr < 4; rr++) {
            const float sc = exp2f(lg2 * (float)(16 * w + quad * 4 + rr + 1));
            #pragma unroll
            for (int vt = 0; vt < 8; vt++) y[vt][rr] *= sc;
        }
    }

    __syncthreads();

    f32x4 s4[4];
    #pragma unroll
    for (int kt = 0; kt < 4; kt++) s4[kt] = fzero;
    #pragma unroll
    for (int ks = 0; ks < 4; ks++) {
        #pragma unroll
        for (int kt = 0; kt < 4; kt++) {
            bf16x8 bk = *(const bf16x8*)&Ks[(kt * 16 + ln) * 136 + ks * 32 + quad * 8];
            s4[kt] = __builtin_amdgcn_mfma_f32_16x16x32_bf16(bk, aq[ks], s4[kt], 0, 0, 0);
        }
    }
    const float dq = exp2f((float)(16 * w + ln) * lg2);
    #pragma unroll
    for (int kt = 0; kt < 4; kt++) {
        const float db = dq * dmk[kt];
        ushort4 pk;
        pk.x = f2bf((kt * 16 + quad * 4 + 0 <= 16 * w + ln) ? s4[kt][0] * db * drr[0] : 0.f);
        pk.y = f2bf((kt * 16 + quad * 4 + 1 <= 16 * w + ln) ? s4[kt][1] * db * drr[1] : 0.f);
        pk.z = f2bf((kt * 16 + quad * 4 + 2 <= 16 * w + ln) ? s4[kt][2] * db * drr[2] : 0.f);
        pk.w = f2bf((kt * 16 + quad * 4 + 3 <= 16 * w + ln) ? s4[kt][3] * db * drr[3] : 0.f);
        *(ushort4*)&Ss[(16 * w + ln) * 72 + kt * 16 + quad * 4] = pk;
    }
    #pragma unroll
    for (int ks2 = 0; ks2 < 2; ks2++) {
        bf16x8 as = *(const bf16x8*)&Ss[(16 * w + ln) * 72 + ks2 * 32 + quad * 8];
        #pragma unroll
        for (int vt = 0; vt < 8; vt++) {
            bf16x8 bv = *(const bf16x8*)&Vs[(vt * 16 + ln) * 72 + ks2 * 32 + quad * 8];
            y[vt] = __builtin_amdgcn_mfma_f32_16x16x32_bf16(as, bv, y[vt], 0, 0, 0);
        }
    }

    #pragma unroll
    for (int r = 0; r < 4; r++) {
        float s = 0.f, sq = 0.f;
        #pragma unroll
        for (int vt = 0; vt < 8; vt++) {
            float v = y[vt][r];
            s += v; sq += v * v;
        }
        #pragma unroll
        for (int off = 8; off >= 1; off >>= 1) {
            s  += __shfl_xor(s, off, 64);
            sq += __shfl_xor(sq, off, 64);
        }
        float mean = s * 0.0078125f;
        float var = sq * 0.0078125f - mean * mean;
        float rstd = rsqrtf(var + 1e-5f);
        const size_t row = (size_t)(b * LL + n0 + 16 * w + quad * 4 + r);
        #pragma unroll
        for (int vt = 0; vt < 8; vt++) {
            float gv = bf2f(Gb[row * 1024 + h * 128 + vt * 16 + ln]);
            float o = (y[vt][r] - mean) * rstd * gwv[vt] + gbv[vt];
            Z[row * 1024 + h * 128 + vt * 16 + ln] = f2bf(o * gv);
        }
    }
}

// ---------------------------------------------------------------------------
extern "C" void kernel_launch(void* const* d_in, const int* in_sizes, int n_in,
                              void* d_out, int out_size, void* d_ws, size_t ws_size,
                              hipStream_t stream) {
    const float* X   = (const float*)d_in[0];
    const float* Wq  = (const float*)d_in[1];
    const float* Wk  = (const float*)d_in[2];
    const float* Wv  = (const float*)d_in[3];
    const float* Wg  = (const float*)d_in[4];
    const float* Wo  = (const float*)d_in[5];
    const float* gnw = (const float*)d_in[6];
    const float* gnb = (const float*)d_in[7];
    float* out = (float*)d_out;

    const size_t MB = 1u << 20;
    char* base = (char*)d_ws;
    // Sb (32 MB, 0-32) overlays tbl/Xb/Wq..Wg, which die after the QKVG mm.
    ushort* Sb  = (ushort*)base;                        // 0-32  (L then P, bf16)
    float4* tbl = (float4*)base;                        // 0-2
    ushort* Xb  = (ushort*)(base + 2 * MB);             // 2-18
    ushort* Wqt = (ushort*)(base + 18 * MB);
    ushort* Wkt = (ushort*)(base + 20 * MB);
    ushort* Wvt = (ushort*)(base + 22 * MB);
    ushort* Wgt = (ushort*)(base + 24 * MB);
    ushort* Wot = (ushort*)(base + 32 * MB);            // 32-34
    ushort* Qb  = (ushort*)(base + 34 * MB);            // 34-50
    ushort* Kb  = (ushort*)(base + 50 * MB);            // 50-66
    ushort* Gb  = (ushort*)(base + 66 * MB);            // 66-82
    ushort* Vt  = (ushort*)(base + 82 * MB);            // 82-98
    ushort* Ktb = (ushort*)(base + 98 * MB);            // 98-114 (dead after R1)
    ushort* Zb  = (ushort*)(base + 98 * MB);            // reuses Ktb region in R3+

    Gammas gp;
    for (int h = 0; h < 8; h++) {
        double lin = log(1.0 / 32.0) +
                     (log(1.0 / 512.0) - log(1.0 / 32.0)) * (double)h / 7.0;
        float gamma = 1.0f - expf((float)lin);
        gp.lg2[h] = log2f(gamma);
    }

    // single prep launch: xpos table + cast + all 5 weight transposes
    PrepArgs pa;
    pa.W[0] = Wq;  pa.Wt[0] = Wqt; pa.perhead[0] = 1;
    pa.W[1] = Wk;  pa.Wt[1] = Wkt; pa.perhead[1] = 1;
    pa.W[2] = Wv;  pa.Wt[2] = Wvt; pa.perhead[2] = 1;
    pa.W[3] = Wg;  pa.Wt[3] = Wgt; pa.perhead[3] = 0;
    pa.W[4] = Wo;  pa.Wt[4] = Wot; pa.perhead[4] = 0;
    prep_kernel<<<9984, 256, 0, stream>>>(X, Xb, tbl, pa);

    // fused Q/K/V/G projections; K emits row-major Kb AND transposed K~t
    MMArgs qa;
    qa.Bt[0] = Wqt; qa.Bt[1] = Wkt; qa.Bt[2] = Wvt; qa.Bt[3] = Wgt;
    qa.C[0] = Qb;   qa.C[1] = Kb;   qa.C[2] = Vt;   qa.C[3] = Gb;
    qa.C2[0] = nullptr; qa.C2[1] = Ktb; qa.C2[2] = nullptr; qa.C2[3] = nullptr;
    qa.emode[0] = 1; qa.emode[1] = 6; qa.emode[2] = 5; qa.emode[3] = 3;
    mm_kernel<<<dim3(32, 64), 256, 0, stream>>>(Xb, qa, tbl);

    // chunked-recurrent retention: local states -> scan -> per-chunk output
    state_kernel<<<dim3(32, 32), 256, 0, stream>>>(Ktb, Vt, Sb, gp);
    scan_kernel<<<dim3(8, 32), 256, 0, stream>>>(Sb, gp);
    ret2_kernel<<<dim3(32, 32), 256, 0, stream>>>(Qb, Kb, Vt, Sb, Gb,
                                                  gnw, gnb, Zb, gp);

    MMArgs oa;
    oa.Bt[0] = Wot; oa.Bt[1] = Wot; oa.Bt[2] = Wot; oa.Bt[3] = Wot;
    oa.C[0] = out;  oa.C[1] = out;  oa.C[2] = out;  oa.C[3] = out;
    oa.C2[0] = nullptr; oa.C2[1] = nullptr; oa.C2[2] = nullptr; oa.C2[3] = nullptr;
    oa.emode[0] = 4; oa.emode[1] = 4; oa.emode[2] = 4; oa.emode[3] = 4;
    mm_kernel<<<dim3(8, 64), 256, 0, stream>>>(Zb, oa, tbl);
}